// Round 1
// baseline (675.252 us; speedup 1.0000x reference)
//
#include <hip/hip_runtime.h>

typedef __bf16 bf16;
typedef __bf16 bf16x8 __attribute__((ext_vector_type(8)));
typedef __bf16 bf16x4 __attribute__((ext_vector_type(4)));
typedef float f32x4 __attribute__((ext_vector_type(4)));

#define MFMA(a, b, c) __builtin_amdgcn_mfma_f32_16x16x32_bf16(a, b, c, 0, 0, 0)

__device__ __forceinline__ void g2l16(void* lds, const void* g) {
  __builtin_amdgcn_global_load_lds(
      (const __attribute__((address_space(1))) void*)g,
      (__attribute__((address_space(3))) void*)lds, 16, 0, 0);
}

// ---------------- fp32 -> bf16 conversion ----------------
__global__ void cvt4_kernel(const float* __restrict__ src, bf16* __restrict__ dst, int n4) {
  int i = blockIdx.x * 256 + threadIdx.x;
  if (i >= n4) return;
  f32x4 v = *(const f32x4*)(src + i * 4);
  bf16x4 d;
  d[0] = (bf16)v[0]; d[1] = (bf16)v[1]; d[2] = (bf16)v[2]; d[3] = (bf16)v[3];
  *(bf16x4*)(dst + i * 4) = d;
}

// ---------------- pos = pe @ Wp^T + bp (fp32 out) ----------------
__global__ __launch_bounds__(256) void gemm_pos(
    const bf16* __restrict__ peb, const bf16* __restrict__ Wpb,
    const float* __restrict__ bp, float* __restrict__ pos) {
  __shared__ bf16 smA[128 * 32];
  __shared__ bf16 smB[128 * 32];
  const int mbase = blockIdx.y * 128;
  const int nbase = blockIdx.x * 128;
  const int tid = threadIdx.x;
  const int lane = tid & 63, w = tid >> 6;
  const int wm = (w >> 1) * 64, wn = (w & 1) * 64;
  const int lrow = lane & 15, kg = lane >> 4;
  const f32x4 fz = {0.f, 0.f, 0.f, 0.f};
  f32x4 acc[4][4];
#pragma unroll
  for (int i = 0; i < 4; ++i)
#pragma unroll
    for (int j = 0; j < 4; ++j) acc[i][j] = fz;

  for (int k0 = 0; k0 < 1024; k0 += 32) {
    __syncthreads();
#pragma unroll
    for (int it = 0; it < 2; ++it) {
      int j = it * 256 + tid;
      int r = j >> 2, cl = j & 3;
      int c = cl ^ ((r >> 1) & 3);
      if (mbase + r < 400)
        g2l16(smA + j * 8, peb + (mbase + r) * 1024 + k0 + c * 8);
      else {
        uint4 zz = make_uint4(0, 0, 0, 0);
        *(uint4*)(smA + j * 8) = zz;
      }
    }
#pragma unroll
    for (int it = 0; it < 2; ++it) {
      int j = it * 256 + tid;
      int r = j >> 2, cl = j & 3;
      int c = cl ^ ((r >> 1) & 3);
      g2l16(smB + j * 8, Wpb + (nbase + r) * 1024 + k0 + c * 8);
    }
    __syncthreads();
    bf16x8 af[4], bfr[4];
#pragma unroll
    for (int mt = 0; mt < 4; ++mt) {
      int r = wm + mt * 16 + lrow;
      int ch = kg ^ ((r >> 1) & 3);
      af[mt] = *(const bf16x8*)(smA + r * 32 + ch * 8);
    }
#pragma unroll
    for (int nt = 0; nt < 4; ++nt) {
      int r = wn + nt * 16 + lrow;
      int ch = kg ^ ((r >> 1) & 3);
      bfr[nt] = *(const bf16x8*)(smB + r * 32 + ch * 8);
    }
#pragma unroll
    for (int nt = 0; nt < 4; ++nt)
#pragma unroll
      for (int mt = 0; mt < 4; ++mt)
        acc[mt][nt] = MFMA(af[mt], bfr[nt], acc[mt][nt]);
  }
#pragma unroll
  for (int mt = 0; mt < 4; ++mt)
#pragma unroll
    for (int rg = 0; rg < 4; ++rg) {
      int m = mbase + wm + mt * 16 + kg * 4 + rg;
      if (m < 400) {
#pragma unroll
        for (int nt = 0; nt < 4; ++nt) {
          int n = nbase + wn + nt * 16 + lrow;
          pos[m * 1024 + n] = acc[mt][nt][rg] + bp[n];
        }
      }
    }
}

// ---------------- QKV projection (A fp32, B bf16 weights) ----------------
__global__ __launch_bounds__(256) void gemm_qkv(
    const float* __restrict__ Xq, const float* __restrict__ Xk, const float* __restrict__ Xv,
    const bf16* __restrict__ Wqb, const bf16* __restrict__ Wkb, const bf16* __restrict__ Wvb,
    const float* __restrict__ bq, const float* __restrict__ bk, const float* __restrict__ bv,
    const float* __restrict__ pos, bf16* __restrict__ qb, bf16* __restrict__ kbuf,
    bf16* __restrict__ vt) {
  __shared__ float smA[128 * 32];
  __shared__ bf16 smB[128 * 32];
  const int z = blockIdx.z;
  const float* X = (z == 0) ? Xq : (z == 1) ? Xk : Xv;
  const bf16* W = (z == 0) ? Wqb : (z == 1) ? Wkb : Wvb;
  const float* bias = (z == 0) ? bq : (z == 1) ? bk : bv;
  const int mbase = blockIdx.y * 128;
  const int nbase = blockIdx.x * 128;
  const int tid = threadIdx.x;
  const int lane = tid & 63, w = tid >> 6;
  const int wm = (w >> 1) * 64, wn = (w & 1) * 64;
  const int lrow = lane & 15, kg = lane >> 4;
  const f32x4 fz = {0.f, 0.f, 0.f, 0.f};
  f32x4 acc[4][4];
#pragma unroll
  for (int i = 0; i < 4; ++i)
#pragma unroll
    for (int j = 0; j < 4; ++j) acc[i][j] = fz;

  for (int k0 = 0; k0 < 1024; k0 += 32) {
    __syncthreads();
#pragma unroll
    for (int it = 0; it < 4; ++it) {
      int j = it * 256 + tid;
      int r = j >> 3, cl = j & 7;
      int c = cl ^ (r & 7);
      g2l16(smA + j * 4, X + (mbase + r) * 1024 + k0 + c * 4);
    }
#pragma unroll
    for (int it = 0; it < 2; ++it) {
      int j = it * 256 + tid;
      int r = j >> 2, cl = j & 3;
      int c = cl ^ ((r >> 1) & 3);
      g2l16(smB + j * 8, W + (nbase + r) * 1024 + k0 + c * 8);
    }
    __syncthreads();
    bf16x8 af[4], bfr[4];
#pragma unroll
    for (int mt = 0; mt < 4; ++mt) {
      int r = wm + mt * 16 + lrow;
      int c0 = (2 * kg) ^ (r & 7);
      int c1 = (2 * kg + 1) ^ (r & 7);
      f32x4 lo = *(const f32x4*)(smA + r * 32 + c0 * 4);
      f32x4 hi = *(const f32x4*)(smA + r * 32 + c1 * 4);
      bf16x8 a;
      a[0] = (bf16)lo[0]; a[1] = (bf16)lo[1]; a[2] = (bf16)lo[2]; a[3] = (bf16)lo[3];
      a[4] = (bf16)hi[0]; a[5] = (bf16)hi[1]; a[6] = (bf16)hi[2]; a[7] = (bf16)hi[3];
      af[mt] = a;
    }
#pragma unroll
    for (int nt = 0; nt < 4; ++nt) {
      int r = wn + nt * 16 + lrow;
      int ch = kg ^ ((r >> 1) & 3);
      bfr[nt] = *(const bf16x8*)(smB + r * 32 + ch * 8);
    }
#pragma unroll
    for (int nt = 0; nt < 4; ++nt)
#pragma unroll
      for (int mt = 0; mt < 4; ++mt)
        acc[mt][nt] = MFMA(af[mt], bfr[nt], acc[mt][nt]);
  }
#pragma unroll
  for (int mt = 0; mt < 4; ++mt)
#pragma unroll
    for (int rg = 0; rg < 4; ++rg) {
      int m = mbase + wm + mt * 16 + kg * 4 + rg;
      int bI = m / 400;
      int s = m - bI * 400;
#pragma unroll
      for (int nt = 0; nt < 4; ++nt) {
        int n = nbase + wn + nt * 16 + lrow;
        float v = acc[mt][nt][rg] + bias[n] + pos[s * 1024 + n];
        int h = n >> 6, d = n & 63;
        if (z == 2)
          vt[((bI * 16 + h) * 64 + d) * 400 + s] = (bf16)v;
        else {
          bf16* dst = (z == 0) ? qb : kbuf;
          dst[((bI * 16 + h) * 400 + s) * 64 + d] = (bf16)v;
        }
      }
    }
}

// ---------------- flash attention ----------------
__global__ __launch_bounds__(256) void attn_kernel(
    const bf16* __restrict__ qg, const bf16* __restrict__ kg_,
    const bf16* __restrict__ vg, const float* __restrict__ mask,
    bf16* __restrict__ ao) {
  __shared__ bf16 smQ[64 * 64];    // 8 KB
  __shared__ bf16 smK[128 * 64];   // 16 KB
  __shared__ bf16 smV[64 * 128];   // 16 KB (V^T: [d][s])
  __shared__ bf16 smP[64 * 128];   // 16 KB
  const int qt = blockIdx.x;       // 0..6
  const int bh = blockIdx.y;       // 0..511
  const int qbase = qt * 64;
  const int tid = threadIdx.x;
  const int lane = tid & 63;
  const int w = tid >> 6;
  const int lrow = lane & 15, kg = lane >> 4;
  const bf16* Qg = qg + bh * 25600;
  const bf16* Kg = kg_ + bh * 25600;
  const bf16* Vg = vg + bh * 25600;

  // stage Q (64 x 64), swizzled
#pragma unroll
  for (int it = 0; it < 2; ++it) {
    int j = it * 256 + tid;
    int r = j >> 3, cl = j & 7;
    int c = cl ^ (r & 7);
    int s = qbase + r;
    uint4 val = make_uint4(0, 0, 0, 0);
    if (s < 400) val = *(const uint4*)(Qg + s * 64 + c * 8);
    *(uint4*)(smQ + j * 8) = val;
  }

  const f32x4 fz = {0.f, 0.f, 0.f, 0.f};
  f32x4 o[4];
#pragma unroll
  for (int i = 0; i < 4; ++i) o[i] = fz;
  float m_run[4], l_run[4];
#pragma unroll
  for (int i = 0; i < 4; ++i) { m_run[i] = -1e30f; l_run[i] = 0.f; }

  for (int kt = 0; kt < 4; ++kt) {
    // stage K (128 x 64)
#pragma unroll
    for (int it = 0; it < 4; ++it) {
      int j = it * 256 + tid;
      int r = j >> 3, cl = j & 7;
      int c = cl ^ (r & 7);
      int s = kt * 128 + r;
      uint4 val = make_uint4(0, 0, 0, 0);
      if (s < 400) val = *(const uint4*)(Kg + s * 64 + c * 8);
      *(uint4*)(smK + j * 8) = val;
    }
    // stage V^T (64 d x 128 s)
#pragma unroll
    for (int it = 0; it < 4; ++it) {
      int j = it * 256 + tid;
      int r = j >> 4, cl = j & 15;
      int c = cl ^ (r & 15);
      int s0 = kt * 128 + c * 8;
      uint4 val = make_uint4(0, 0, 0, 0);
      if (s0 < 400) val = *(const uint4*)(Vg + r * 400 + s0);
      *(uint4*)(smV + j * 8) = val;
    }
    __syncthreads();

    // QK^T: this wave's 16 q-rows x 128 k-cols
    f32x4 sc[8];
#pragma unroll
    for (int nt = 0; nt < 8; ++nt) sc[nt] = fz;
#pragma unroll
    for (int ks = 0; ks < 2; ++ks) {
      int rq = w * 16 + lrow;
      int chq = (ks * 4 + kg) ^ (rq & 7);
      bf16x8 aq = *(const bf16x8*)(smQ + rq * 64 + chq * 8);
#pragma unroll
      for (int nt = 0; nt < 8; ++nt) {
        int rk = nt * 16 + lrow;
        int chk = (ks * 4 + kg) ^ (rk & 7);
        bf16x8 bk8 = *(const bf16x8*)(smK + rk * 64 + chk * 8);
        sc[nt] = MFMA(aq, bk8, sc[nt]);
      }
    }
    // online softmax
    float alpha[4];
#pragma unroll
    for (int rg = 0; rg < 4; ++rg) {
      int qs = qbase + w * 16 + kg * 4 + rg;
      float rmax = -1e30f;
#pragma unroll
      for (int nt = 0; nt < 8; ++nt) {
        int ksi = kt * 128 + nt * 16 + lrow;
        float v = sc[nt][rg] * 0.125f;
        v += (ksi < 400) ? ((qs < 400) ? mask[qs * 400 + ksi] : 0.f) : -1e30f;
        sc[nt][rg] = v;
        rmax = fmaxf(rmax, v);
      }
#pragma unroll
      for (int off = 1; off < 16; off <<= 1)
        rmax = fmaxf(rmax, __shfl_xor(rmax, off, 64));
      float mn = fmaxf(m_run[rg], rmax);
      alpha[rg] = __expf(m_run[rg] - mn);
      m_run[rg] = mn;
      float rsum = 0.f;
#pragma unroll
      for (int nt = 0; nt < 8; ++nt) {
        float p = __expf(sc[nt][rg] - mn);
        sc[nt][rg] = p;
        rsum += p;
      }
#pragma unroll
      for (int off = 1; off < 16; off <<= 1)
        rsum += __shfl_xor(rsum, off, 64);
      l_run[rg] = l_run[rg] * alpha[rg] + rsum;
    }
#pragma unroll
    for (int nt2 = 0; nt2 < 4; ++nt2)
#pragma unroll
      for (int rg = 0; rg < 4; ++rg) o[nt2][rg] *= alpha[rg];
    // write P (bf16) to per-wave-private LDS rows, swizzled
#pragma unroll
    for (int nt = 0; nt < 8; ++nt)
#pragma unroll
      for (int rg = 0; rg < 4; ++rg) {
        int row = w * 16 + kg * 4 + rg;
        int col = nt * 16 + lrow;
        int ch = (col >> 3) ^ (row & 15);
        smP[row * 128 + ch * 8 + (col & 7)] = (bf16)sc[nt][rg];
      }
    __syncthreads();
    // P @ V
#pragma unroll
    for (int ks2 = 0; ks2 < 4; ++ks2) {
      int rp = w * 16 + lrow;
      int chp = (ks2 * 4 + kg) ^ (rp & 15);
      bf16x8 ap = *(const bf16x8*)(smP + rp * 128 + chp * 8);
#pragma unroll
      for (int nt2 = 0; nt2 < 4; ++nt2) {
        int rv = nt2 * 16 + lrow;
        int chv = (ks2 * 4 + kg) ^ (rv & 15);
        bf16x8 bv8 = *(const bf16x8*)(smV + rv * 128 + chv * 8);
        o[nt2] = MFMA(ap, bv8, o[nt2]);
      }
    }
    __syncthreads();
  }
  const int b = bh >> 4, h = bh & 15;
#pragma unroll
  for (int rg = 0; rg < 4; ++rg) {
    int qs = qbase + w * 16 + kg * 4 + rg;
    if (qs < 400) {
      float inv = 1.f / l_run[rg];
#pragma unroll
      for (int nt2 = 0; nt2 < 4; ++nt2) {
        ao[(b * 400 + qs) * 1024 + h * 64 + nt2 * 16 + lrow] =
            (bf16)(o[nt2][rg] * inv);
      }
    }
  }
}

// ---------------- output projection ----------------
__global__ __launch_bounds__(256) void gemm_out(
    const bf16* __restrict__ aop, const bf16* __restrict__ Wob,
    const float* __restrict__ bo, const float* __restrict__ gates,
    float* __restrict__ out) {
  __shared__ bf16 smA[128 * 32];
  __shared__ bf16 smB[128 * 32];
  const int mbase = blockIdx.y * 128;
  const int nbase = blockIdx.x * 128;
  const int tid = threadIdx.x;
  const int lane = tid & 63, w = tid >> 6;
  const int wm = (w >> 1) * 64, wn = (w & 1) * 64;
  const int lrow = lane & 15, kg = lane >> 4;
  const float g = gates[0];
  const f32x4 fz = {0.f, 0.f, 0.f, 0.f};
  f32x4 acc[4][4];
#pragma unroll
  for (int i = 0; i < 4; ++i)
#pragma unroll
    for (int j = 0; j < 4; ++j) acc[i][j] = fz;

  for (int k0 = 0; k0 < 1024; k0 += 32) {
    __syncthreads();
#pragma unroll
    for (int it = 0; it < 2; ++it) {
      int j = it * 256 + tid;
      int r = j >> 2, cl = j & 3;
      int c = cl ^ ((r >> 1) & 3);
      g2l16(smA + j * 8, aop + (mbase + r) * 1024 + k0 + c * 8);
    }
#pragma unroll
    for (int it = 0; it < 2; ++it) {
      int j = it * 256 + tid;
      int r = j >> 2, cl = j & 3;
      int c = cl ^ ((r >> 1) & 3);
      g2l16(smB + j * 8, Wob + (nbase + r) * 1024 + k0 + c * 8);
    }
    __syncthreads();
    bf16x8 af[4], bfr[4];
#pragma unroll
    for (int mt = 0; mt < 4; ++mt) {
      int r = wm + mt * 16 + lrow;
      int ch = kg ^ ((r >> 1) & 3);
      af[mt] = *(const bf16x8*)(smA + r * 32 + ch * 8);
    }
#pragma unroll
    for (int nt = 0; nt < 4; ++nt) {
      int r = wn + nt * 16 + lrow;
      int ch = kg ^ ((r >> 1) & 3);
      bfr[nt] = *(const bf16x8*)(smB + r * 32 + ch * 8);
    }
#pragma unroll
    for (int nt = 0; nt < 4; ++nt)
#pragma unroll
      for (int mt = 0; mt < 4; ++mt)
        acc[mt][nt] = MFMA(af[mt], bfr[nt], acc[mt][nt]);
  }
#pragma unroll
  for (int mt = 0; mt < 4; ++mt)
#pragma unroll
    for (int rg = 0; rg < 4; ++rg) {
      int m = mbase + wm + mt * 16 + kg * 4 + rg;
#pragma unroll
      for (int nt = 0; nt < 4; ++nt) {
        int n = nbase + wn + nt * 16 + lrow;
        out[m * 1024 + n] = (acc[mt][nt][rg] + bo[n]) * g;
      }
    }
}

extern "C" void kernel_launch(void* const* d_in, const int* in_sizes, int n_in,
                              void* d_out, int out_size, void* d_ws, size_t ws_size,
                              hipStream_t stream) {
  const float* query = (const float*)d_in[0];
  const float* key   = (const float*)d_in[1];
  const float* value = (const float*)d_in[2];
  const float* mask  = (const float*)d_in[3];
  const float* pe    = (const float*)d_in[4];
  const float* Wq = (const float*)d_in[5];
  const float* bq = (const float*)d_in[6];
  const float* Wk = (const float*)d_in[7];
  const float* bk = (const float*)d_in[8];
  const float* Wv = (const float*)d_in[9];
  const float* bv = (const float*)d_in[10];
  const float* Wp = (const float*)d_in[11];
  const float* bp = (const float*)d_in[12];
  const float* Wo = (const float*)d_in[13];
  const float* bo = (const float*)d_in[14];
  const float* gates = (const float*)d_in[15];
  float* out = (float*)d_out;

  char* base = (char*)d_ws;
  size_t off = 0;
  bf16* wq_b = (bf16*)(base + off); off += 2097152;
  bf16* wk_b = (bf16*)(base + off); off += 2097152;
  bf16* wv_b = (bf16*)(base + off); off += 2097152;
  bf16* wo_b = (bf16*)(base + off); off += 2097152;
  bf16* wp_b = (bf16*)(base + off); off += 2097152;
  bf16* pe_b = (bf16*)(base + off); off += 819200;
  float* pos = (float*)(base + off); off += 1638400;
  bf16* qb = (bf16*)(base + off); off += 26214400;
  bf16* kb = (bf16*)(base + off); off += 26214400;
  bf16* vt = (bf16*)(base + off); off += 26214400;
  bf16* ao = (bf16*)(base + off); off += 26214400;
  (void)ws_size; (void)in_sizes; (void)n_in; (void)out_size;

  cvt4_kernel<<<1024, 256, 0, stream>>>(Wq, wq_b, 262144);
  cvt4_kernel<<<1024, 256, 0, stream>>>(Wk, wk_b, 262144);
  cvt4_kernel<<<1024, 256, 0, stream>>>(Wv, wv_b, 262144);
  cvt4_kernel<<<1024, 256, 0, stream>>>(Wo, wo_b, 262144);
  cvt4_kernel<<<1024, 256, 0, stream>>>(Wp, wp_b, 262144);
  cvt4_kernel<<<400, 256, 0, stream>>>(pe, pe_b, 102400);

  gemm_pos<<<dim3(8, 4), 256, 0, stream>>>(pe_b, wp_b, bp, pos);
  gemm_qkv<<<dim3(8, 100, 3), 256, 0, stream>>>(query, key, value, wq_b, wk_b, wv_b,
                                                bq, bk, bv, pos, qb, kb, vt);
  attn_kernel<<<dim3(7, 512), 256, 0, stream>>>(qb, kb, vt, mask, ao);
  gemm_out<<<dim3(8, 100), 256, 0, stream>>>(ao, wo_b, bo, gates, out);
}

// Round 2
// 628.473 us; speedup vs baseline: 1.0744x; 1.0744x over previous
//
#include <hip/hip_runtime.h>

typedef __bf16 bf16;
typedef __bf16 bf16x8 __attribute__((ext_vector_type(8)));
typedef __bf16 bf16x4 __attribute__((ext_vector_type(4)));
typedef float f32x4 __attribute__((ext_vector_type(4)));

#define MFMA(a, b, c) __builtin_amdgcn_mfma_f32_16x16x32_bf16(a, b, c, 0, 0, 0)

__device__ __forceinline__ void g2l16(void* lds, const void* g) {
  __builtin_amdgcn_global_load_lds(
      (const __attribute__((address_space(1))) void*)g,
      (__attribute__((address_space(3))) void*)lds, 16, 0, 0);
}

// ---------------- fused fp32 -> bf16 conversion (X, weights, pe) ----------------
// blocks: [0,38400) X q/k/v (12800 each); [38400,43520) 5 weights (1024 each);
// [43520,43920) pe first 400 rows.
__global__ void cvt_all(
    const float* __restrict__ xq, const float* __restrict__ xk, const float* __restrict__ xv,
    const float* __restrict__ Wq, const float* __restrict__ Wk, const float* __restrict__ Wv,
    const float* __restrict__ Wo, const float* __restrict__ Wp, const float* __restrict__ pe,
    bf16* __restrict__ xqb, bf16* __restrict__ xkb, bf16* __restrict__ xvb,
    bf16* __restrict__ wqb, bf16* __restrict__ wkb, bf16* __restrict__ wvb,
    bf16* __restrict__ wob, bf16* __restrict__ wpb, bf16* __restrict__ peb) {
  int b = blockIdx.x;
  const float* s;
  bf16* d;
  int lb;
  if (b < 38400) {
    int t = b / 12800;
    lb = b - t * 12800;
    s = (t == 0) ? xq : (t == 1) ? xk : xv;
    d = (t == 0) ? xqb : (t == 1) ? xkb : xvb;
  } else if (b < 43520) {
    int t = (b - 38400) >> 10;
    lb = (b - 38400) & 1023;
    s = (t == 0) ? Wq : (t == 1) ? Wk : (t == 2) ? Wv : (t == 3) ? Wo : Wp;
    d = (t == 0) ? wqb : (t == 1) ? wkb : (t == 2) ? wvb : (t == 3) ? wob : wpb;
  } else {
    lb = b - 43520;
    s = pe;
    d = peb;
  }
  int i = lb * 256 + threadIdx.x;
  f32x4 v = *(const f32x4*)(s + i * 4);
  bf16x4 o;
  o[0] = (bf16)v[0]; o[1] = (bf16)v[1]; o[2] = (bf16)v[2]; o[3] = (bf16)v[3];
  *(bf16x4*)(d + i * 4) = o;
}

// ---------------- pos = pe @ Wp^T + bp (fp32 out) ----------------
__global__ __launch_bounds__(256) void gemm_pos(
    const bf16* __restrict__ peb, const bf16* __restrict__ Wpb,
    const float* __restrict__ bp, float* __restrict__ pos) {
  __shared__ bf16 smA[128 * 32];
  __shared__ bf16 smB[128 * 32];
  const int mbase = blockIdx.y * 128;
  const int nbase = blockIdx.x * 128;
  const int tid = threadIdx.x;
  const int lane = tid & 63, w = tid >> 6;
  const int wm = (w >> 1) * 64, wn = (w & 1) * 64;
  const int lrow = lane & 15, kg = lane >> 4;
  const f32x4 fz = {0.f, 0.f, 0.f, 0.f};
  f32x4 acc[4][4];
#pragma unroll
  for (int i = 0; i < 4; ++i)
#pragma unroll
    for (int j = 0; j < 4; ++j) acc[i][j] = fz;

  for (int k0 = 0; k0 < 1024; k0 += 32) {
    __syncthreads();
#pragma unroll
    for (int it = 0; it < 2; ++it) {
      int j = it * 256 + tid;
      int r = j >> 2, cl = j & 3;
      int c = cl ^ ((r >> 1) & 3);
      if (mbase + r < 400)
        g2l16(smA + j * 8, peb + (mbase + r) * 1024 + k0 + c * 8);
      else {
        uint4 zz = make_uint4(0, 0, 0, 0);
        *(uint4*)(smA + j * 8) = zz;
      }
    }
#pragma unroll
    for (int it = 0; it < 2; ++it) {
      int j = it * 256 + tid;
      int r = j >> 2, cl = j & 3;
      int c = cl ^ ((r >> 1) & 3);
      g2l16(smB + j * 8, Wpb + (nbase + r) * 1024 + k0 + c * 8);
    }
    __syncthreads();
    bf16x8 af[4], bfr[4];
#pragma unroll
    for (int mt = 0; mt < 4; ++mt) {
      int r = wm + mt * 16 + lrow;
      int ch = kg ^ ((r >> 1) & 3);
      af[mt] = *(const bf16x8*)(smA + r * 32 + ch * 8);
    }
#pragma unroll
    for (int nt = 0; nt < 4; ++nt) {
      int r = wn + nt * 16 + lrow;
      int ch = kg ^ ((r >> 1) & 3);
      bfr[nt] = *(const bf16x8*)(smB + r * 32 + ch * 8);
    }
#pragma unroll
    for (int nt = 0; nt < 4; ++nt)
#pragma unroll
      for (int mt = 0; mt < 4; ++mt)
        acc[mt][nt] = MFMA(af[mt], bfr[nt], acc[mt][nt]);
  }
#pragma unroll
  for (int mt = 0; mt < 4; ++mt)
#pragma unroll
    for (int rg = 0; rg < 4; ++rg) {
      int m = mbase + wm + mt * 16 + kg * 4 + rg;
      if (m < 400) {
#pragma unroll
        for (int nt = 0; nt < 4; ++nt) {
          int n = nbase + wn + nt * 16 + lrow;
          pos[m * 1024 + n] = acc[mt][nt][rg] + bp[n];
        }
      }
    }
}

// ---------------- QKV projection (A bf16, B bf16 weights) ----------------
// grid (100, 8, 3): m-tile on x (fastest) so blocks sharing an A-strip map to
// <=2 XCDs; B column-strips (2 MB) fit in every XCD L2.
__global__ __launch_bounds__(256) void gemm_qkv(
    const bf16* __restrict__ Xq, const bf16* __restrict__ Xk, const bf16* __restrict__ Xv,
    const bf16* __restrict__ Wqb, const bf16* __restrict__ Wkb, const bf16* __restrict__ Wvb,
    const float* __restrict__ bq, const float* __restrict__ bk, const float* __restrict__ bv,
    const float* __restrict__ pos, bf16* __restrict__ qb, bf16* __restrict__ kbuf,
    bf16* __restrict__ vt) {
  __shared__ bf16 smA[128 * 32];
  __shared__ bf16 smB[128 * 32];
  const int z = blockIdx.z;
  const bf16* X = (z == 0) ? Xq : (z == 1) ? Xk : Xv;
  const bf16* W = (z == 0) ? Wqb : (z == 1) ? Wkb : Wvb;
  const float* bias = (z == 0) ? bq : (z == 1) ? bk : bv;
  const int mbase = blockIdx.x * 128;
  const int nbase = blockIdx.y * 128;
  const int tid = threadIdx.x;
  const int lane = tid & 63, w = tid >> 6;
  const int wm = (w >> 1) * 64, wn = (w & 1) * 64;
  const int lrow = lane & 15, kg = lane >> 4;
  const f32x4 fz = {0.f, 0.f, 0.f, 0.f};
  f32x4 acc[4][4];
#pragma unroll
  for (int i = 0; i < 4; ++i)
#pragma unroll
    for (int j = 0; j < 4; ++j) acc[i][j] = fz;

  for (int k0 = 0; k0 < 1024; k0 += 32) {
    __syncthreads();
#pragma unroll
    for (int it = 0; it < 2; ++it) {
      int j = it * 256 + tid;
      int r = j >> 2, cl = j & 3;
      int c = cl ^ ((r >> 1) & 3);
      g2l16(smA + j * 8, X + (mbase + r) * 1024 + k0 + c * 8);
    }
#pragma unroll
    for (int it = 0; it < 2; ++it) {
      int j = it * 256 + tid;
      int r = j >> 2, cl = j & 3;
      int c = cl ^ ((r >> 1) & 3);
      g2l16(smB + j * 8, W + (nbase + r) * 1024 + k0 + c * 8);
    }
    __syncthreads();
    bf16x8 af[4], bfr[4];
#pragma unroll
    for (int mt = 0; mt < 4; ++mt) {
      int r = wm + mt * 16 + lrow;
      int ch = kg ^ ((r >> 1) & 3);
      af[mt] = *(const bf16x8*)(smA + r * 32 + ch * 8);
    }
#pragma unroll
    for (int nt = 0; nt < 4; ++nt) {
      int r = wn + nt * 16 + lrow;
      int ch = kg ^ ((r >> 1) & 3);
      bfr[nt] = *(const bf16x8*)(smB + r * 32 + ch * 8);
    }
#pragma unroll
    for (int nt = 0; nt < 4; ++nt)
#pragma unroll
      for (int mt = 0; mt < 4; ++mt)
        acc[mt][nt] = MFMA(af[mt], bfr[nt], acc[mt][nt]);
  }
#pragma unroll
  for (int mt = 0; mt < 4; ++mt)
#pragma unroll
    for (int rg = 0; rg < 4; ++rg) {
      int m = mbase + wm + mt * 16 + kg * 4 + rg;
      int bI = m / 400;
      int s = m - bI * 400;
#pragma unroll
      for (int nt = 0; nt < 4; ++nt) {
        int n = nbase + wn + nt * 16 + lrow;
        float v = acc[mt][nt][rg] + bias[n] + pos[s * 1024 + n];
        int h = n >> 6, d = n & 63;
        if (z == 2)
          vt[((bI * 16 + h) * 64 + d) * 400 + s] = (bf16)v;
        else {
          bf16* dst = (z == 0) ? qb : kbuf;
          dst[((bI * 16 + h) * 400 + s) * 64 + d] = (bf16)v;
        }
      }
    }
}

// ---------------- flash attention ----------------
__global__ __launch_bounds__(256) void attn_kernel(
    const bf16* __restrict__ qg, const bf16* __restrict__ kg_,
    const bf16* __restrict__ vg, const float* __restrict__ mask,
    bf16* __restrict__ ao) {
  __shared__ bf16 smQ[64 * 64];    // 8 KB
  __shared__ bf16 smK[128 * 64];   // 16 KB
  __shared__ bf16 smV[64 * 128];   // 16 KB (V^T: [d][s])
  __shared__ bf16 smP[64 * 128];   // 16 KB
  const int qt = blockIdx.x;       // 0..6
  const int bh = blockIdx.y;       // 0..511
  const int qbase = qt * 64;
  const int tid = threadIdx.x;
  const int lane = tid & 63;
  const int w = tid >> 6;
  const int lrow = lane & 15, kg = lane >> 4;
  const bf16* Qg = qg + bh * 25600;
  const bf16* Kg = kg_ + bh * 25600;
  const bf16* Vg = vg + bh * 25600;

  // stage Q (64 x 64), swizzled
#pragma unroll
  for (int it = 0; it < 2; ++it) {
    int j = it * 256 + tid;
    int r = j >> 3, cl = j & 7;
    int c = cl ^ (r & 7);
    int s = qbase + r;
    uint4 val = make_uint4(0, 0, 0, 0);
    if (s < 400) val = *(const uint4*)(Qg + s * 64 + c * 8);
    *(uint4*)(smQ + j * 8) = val;
  }

  const f32x4 fz = {0.f, 0.f, 0.f, 0.f};
  f32x4 o[4];
#pragma unroll
  for (int i = 0; i < 4; ++i) o[i] = fz;
  float m_run[4], l_run[4];
#pragma unroll
  for (int i = 0; i < 4; ++i) { m_run[i] = -1e30f; l_run[i] = 0.f; }

  for (int kt = 0; kt < 4; ++kt) {
    // stage K (128 x 64)
#pragma unroll
    for (int it = 0; it < 4; ++it) {
      int j = it * 256 + tid;
      int r = j >> 3, cl = j & 7;
      int c = cl ^ (r & 7);
      int s = kt * 128 + r;
      uint4 val = make_uint4(0, 0, 0, 0);
      if (s < 400) val = *(const uint4*)(Kg + s * 64 + c * 8);
      *(uint4*)(smK + j * 8) = val;
    }
    // stage V^T (64 d x 128 s)
#pragma unroll
    for (int it = 0; it < 4; ++it) {
      int j = it * 256 + tid;
      int r = j >> 4, cl = j & 15;
      int c = cl ^ (r & 15);
      int s0 = kt * 128 + c * 8;
      uint4 val = make_uint4(0, 0, 0, 0);
      if (s0 < 400) val = *(const uint4*)(Vg + r * 400 + s0);
      *(uint4*)(smV + j * 8) = val;
    }
    __syncthreads();

    // QK^T: this wave's 16 q-rows x 128 k-cols
    f32x4 sc[8];
#pragma unroll
    for (int nt = 0; nt < 8; ++nt) sc[nt] = fz;
#pragma unroll
    for (int ks = 0; ks < 2; ++ks) {
      int rq = w * 16 + lrow;
      int chq = (ks * 4 + kg) ^ (rq & 7);
      bf16x8 aq = *(const bf16x8*)(smQ + rq * 64 + chq * 8);
#pragma unroll
      for (int nt = 0; nt < 8; ++nt) {
        int rk = nt * 16 + lrow;
        int chk = (ks * 4 + kg) ^ (rk & 7);
        bf16x8 bk8 = *(const bf16x8*)(smK + rk * 64 + chk * 8);
        sc[nt] = MFMA(aq, bk8, sc[nt]);
      }
    }
    // online softmax
    float alpha[4];
#pragma unroll
    for (int rg = 0; rg < 4; ++rg) {
      int qs = qbase + w * 16 + kg * 4 + rg;
      float rmax = -1e30f;
#pragma unroll
      for (int nt = 0; nt < 8; ++nt) {
        int ksi = kt * 128 + nt * 16 + lrow;
        float v = sc[nt][rg] * 0.125f;
        v += (ksi < 400) ? ((qs < 400) ? mask[qs * 400 + ksi] : 0.f) : -1e30f;
        sc[nt][rg] = v;
        rmax = fmaxf(rmax, v);
      }
#pragma unroll
      for (int off = 1; off < 16; off <<= 1)
        rmax = fmaxf(rmax, __shfl_xor(rmax, off, 64));
      float mn = fmaxf(m_run[rg], rmax);
      alpha[rg] = __expf(m_run[rg] - mn);
      m_run[rg] = mn;
      float rsum = 0.f;
#pragma unroll
      for (int nt = 0; nt < 8; ++nt) {
        float p = __expf(sc[nt][rg] - mn);
        sc[nt][rg] = p;
        rsum += p;
      }
#pragma unroll
      for (int off = 1; off < 16; off <<= 1)
        rsum += __shfl_xor(rsum, off, 64);
      l_run[rg] = l_run[rg] * alpha[rg] + rsum;
    }
#pragma unroll
    for (int nt2 = 0; nt2 < 4; ++nt2)
#pragma unroll
      for (int rg = 0; rg < 4; ++rg) o[nt2][rg] *= alpha[rg];
    // write P (bf16) to per-wave-private LDS rows, swizzled
#pragma unroll
    for (int nt = 0; nt < 8; ++nt)
#pragma unroll
      for (int rg = 0; rg < 4; ++rg) {
        int row = w * 16 + kg * 4 + rg;
        int col = nt * 16 + lrow;
        int ch = (col >> 3) ^ (row & 15);
        smP[row * 128 + ch * 8 + (col & 7)] = (bf16)sc[nt][rg];
      }
    __syncthreads();
    // P @ V
#pragma unroll
    for (int ks2 = 0; ks2 < 4; ++ks2) {
      int rp = w * 16 + lrow;
      int chp = (ks2 * 4 + kg) ^ (rp & 15);
      bf16x8 ap = *(const bf16x8*)(smP + rp * 128 + chp * 8);
#pragma unroll
      for (int nt2 = 0; nt2 < 4; ++nt2) {
        int rv = nt2 * 16 + lrow;
        int chv = (ks2 * 4 + kg) ^ (rv & 15);
        bf16x8 bv8 = *(const bf16x8*)(smV + rv * 128 + chv * 8);
        o[nt2] = MFMA(ap, bv8, o[nt2]);
      }
    }
    __syncthreads();
  }
  const int b = bh >> 4, h = bh & 15;
#pragma unroll
  for (int rg = 0; rg < 4; ++rg) {
    int qs = qbase + w * 16 + kg * 4 + rg;
    if (qs < 400) {
      float inv = 1.f / l_run[rg];
#pragma unroll
      for (int nt2 = 0; nt2 < 4; ++nt2) {
        ao[(b * 400 + qs) * 1024 + h * 64 + nt2 * 16 + lrow] =
            (bf16)(o[nt2][rg] * inv);
      }
    }
  }
}

// ---------------- output projection ----------------
__global__ __launch_bounds__(256) void gemm_out(
    const bf16* __restrict__ aop, const bf16* __restrict__ Wob,
    const float* __restrict__ bo, const float* __restrict__ gates,
    float* __restrict__ out) {
  __shared__ bf16 smA[128 * 32];
  __shared__ bf16 smB[128 * 32];
  const int mbase = blockIdx.x * 128;
  const int nbase = blockIdx.y * 128;
  const int tid = threadIdx.x;
  const int lane = tid & 63, w = tid >> 6;
  const int wm = (w >> 1) * 64, wn = (w & 1) * 64;
  const int lrow = lane & 15, kg = lane >> 4;
  const float g = gates[0];
  const f32x4 fz = {0.f, 0.f, 0.f, 0.f};
  f32x4 acc[4][4];
#pragma unroll
  for (int i = 0; i < 4; ++i)
#pragma unroll
    for (int j = 0; j < 4; ++j) acc[i][j] = fz;

  for (int k0 = 0; k0 < 1024; k0 += 32) {
    __syncthreads();
#pragma unroll
    for (int it = 0; it < 2; ++it) {
      int j = it * 256 + tid;
      int r = j >> 2, cl = j & 3;
      int c = cl ^ ((r >> 1) & 3);
      g2l16(smA + j * 8, aop + (mbase + r) * 1024 + k0 + c * 8);
    }
#pragma unroll
    for (int it = 0; it < 2; ++it) {
      int j = it * 256 + tid;
      int r = j >> 2, cl = j & 3;
      int c = cl ^ ((r >> 1) & 3);
      g2l16(smB + j * 8, Wob + (nbase + r) * 1024 + k0 + c * 8);
    }
    __syncthreads();
    bf16x8 af[4], bfr[4];
#pragma unroll
    for (int mt = 0; mt < 4; ++mt) {
      int r = wm + mt * 16 + lrow;
      int ch = kg ^ ((r >> 1) & 3);
      af[mt] = *(const bf16x8*)(smA + r * 32 + ch * 8);
    }
#pragma unroll
    for (int nt = 0; nt < 4; ++nt) {
      int r = wn + nt * 16 + lrow;
      int ch = kg ^ ((r >> 1) & 3);
      bfr[nt] = *(const bf16x8*)(smB + r * 32 + ch * 8);
    }
#pragma unroll
    for (int nt = 0; nt < 4; ++nt)
#pragma unroll
      for (int mt = 0; mt < 4; ++mt)
        acc[mt][nt] = MFMA(af[mt], bfr[nt], acc[mt][nt]);
  }
#pragma unroll
  for (int mt = 0; mt < 4; ++mt)
#pragma unroll
    for (int rg = 0; rg < 4; ++rg) {
      int m = mbase + wm + mt * 16 + kg * 4 + rg;
#pragma unroll
      for (int nt = 0; nt < 4; ++nt) {
        int n = nbase + wn + nt * 16 + lrow;
        out[m * 1024 + n] = (acc[mt][nt][rg] + bo[n]) * g;
      }
    }
}

extern "C" void kernel_launch(void* const* d_in, const int* in_sizes, int n_in,
                              void* d_out, int out_size, void* d_ws, size_t ws_size,
                              hipStream_t stream) {
  const float* query = (const float*)d_in[0];
  const float* key   = (const float*)d_in[1];
  const float* value = (const float*)d_in[2];
  const float* mask  = (const float*)d_in[3];
  const float* pe    = (const float*)d_in[4];
  const float* Wq = (const float*)d_in[5];
  const float* bq = (const float*)d_in[6];
  const float* Wk = (const float*)d_in[7];
  const float* bk = (const float*)d_in[8];
  const float* Wv = (const float*)d_in[9];
  const float* bv = (const float*)d_in[10];
  const float* Wp = (const float*)d_in[11];
  const float* bp = (const float*)d_in[12];
  const float* Wo = (const float*)d_in[13];
  const float* bo = (const float*)d_in[14];
  const float* gates = (const float*)d_in[15];
  float* out = (float*)d_out;

  char* base = (char*)d_ws;
  size_t off = 0;
  bf16* wq_b = (bf16*)(base + off); off += 2097152;
  bf16* wk_b = (bf16*)(base + off); off += 2097152;
  bf16* wv_b = (bf16*)(base + off); off += 2097152;
  bf16* wo_b = (bf16*)(base + off); off += 2097152;
  bf16* wp_b = (bf16*)(base + off); off += 2097152;
  bf16* pe_b = (bf16*)(base + off); off += 819200;
  float* pos = (float*)(base + off); off += 1638400;
  bf16* qb = (bf16*)(base + off); off += 26214400;
  bf16* kb = (bf16*)(base + off); off += 26214400;
  bf16* vt = (bf16*)(base + off); off += 26214400;
  // xq_b shares a slot with ao: xq_b dead before attn writes ao.
  bf16* xq_b = (bf16*)(base + off); off += 26214400;
  bf16* ao = xq_b;
  // xk_b/xv_b live in d_out (52.4 MB): dead before gemm_out writes out.
  bf16* xk_b = (bf16*)d_out;
  bf16* xv_b = (bf16*)((char*)d_out + 26214400);
  (void)ws_size; (void)in_sizes; (void)n_in; (void)out_size;

  cvt_all<<<43920, 256, 0, stream>>>(query, key, value, Wq, Wk, Wv, Wo, Wp, pe,
                                     xq_b, xk_b, xv_b, wq_b, wk_b, wv_b, wo_b,
                                     wp_b, pe_b);
  gemm_pos<<<dim3(8, 4), 256, 0, stream>>>(pe_b, wp_b, bp, pos);
  gemm_qkv<<<dim3(100, 8, 3), 256, 0, stream>>>(xq_b, xk_b, xv_b, wq_b, wk_b, wv_b,
                                                bq, bk, bv, pos, qb, kb, vt);
  attn_kernel<<<dim3(7, 512), 256, 0, stream>>>(qb, kb, vt, mask, ao);
  gemm_out<<<dim3(100, 8), 256, 0, stream>>>(ao, wo_b, bo, gates, out);
}

// Round 3
// 568.248 us; speedup vs baseline: 1.1883x; 1.1060x over previous
//
#include <hip/hip_runtime.h>

typedef __bf16 bf16;
typedef __bf16 bf16x8 __attribute__((ext_vector_type(8)));
typedef __bf16 bf16x4 __attribute__((ext_vector_type(4)));
typedef float f32x4 __attribute__((ext_vector_type(4)));

#define MFMA(a, b, c) __builtin_amdgcn_mfma_f32_16x16x32_bf16(a, b, c, 0, 0, 0)

__device__ __forceinline__ void g2l16(void* lds, const void* g) {
  __builtin_amdgcn_global_load_lds(
      (const __attribute__((address_space(1))) void*)g,
      (__attribute__((address_space(3))) void*)lds, 16, 0, 0);
}

// ---------------- fp32 -> bf16 conversion (weights + pe only) ----------------
// blocks: [0,5120) 5 weights (1024 blocks each); [5120,5520) pe rows 0..399.
__global__ void cvt_all(
    const float* __restrict__ Wq, const float* __restrict__ Wk, const float* __restrict__ Wv,
    const float* __restrict__ Wo, const float* __restrict__ Wp, const float* __restrict__ pe,
    bf16* __restrict__ wqb, bf16* __restrict__ wkb, bf16* __restrict__ wvb,
    bf16* __restrict__ wob, bf16* __restrict__ wpb, bf16* __restrict__ peb) {
  int b = blockIdx.x;
  const float* s;
  bf16* d;
  int lb;
  if (b < 5120) {
    int t = b >> 10;
    lb = b & 1023;
    s = (t == 0) ? Wq : (t == 1) ? Wk : (t == 2) ? Wv : (t == 3) ? Wo : Wp;
    d = (t == 0) ? wqb : (t == 1) ? wkb : (t == 2) ? wvb : (t == 3) ? wob : wpb;
  } else {
    lb = b - 5120;
    s = pe;
    d = peb;
  }
  int i = lb * 256 + threadIdx.x;
  f32x4 v = *(const f32x4*)(s + i * 4);
  bf16x4 o;
  o[0] = (bf16)v[0]; o[1] = (bf16)v[1]; o[2] = (bf16)v[2]; o[3] = (bf16)v[3];
  *(bf16x4*)(d + i * 4) = o;
}

// ---------------- posq/k/v = bf16(pe @ Wp^T + bp + b{q,k,v}) ----------------
__global__ __launch_bounds__(256) void gemm_pos(
    const bf16* __restrict__ peb, const bf16* __restrict__ Wpb,
    const float* __restrict__ bp, const float* __restrict__ bq,
    const float* __restrict__ bk, const float* __restrict__ bv,
    bf16* __restrict__ posq, bf16* __restrict__ posk, bf16* __restrict__ posv) {
  __shared__ bf16 smA[128 * 32];
  __shared__ bf16 smB[128 * 32];
  const int mbase = blockIdx.y * 128;
  const int nbase = blockIdx.x * 128;
  const int tid = threadIdx.x;
  const int lane = tid & 63, w = tid >> 6;
  const int wm = (w >> 1) * 64, wn = (w & 1) * 64;
  const int lrow = lane & 15, kg = lane >> 4;
  const f32x4 fz = {0.f, 0.f, 0.f, 0.f};
  f32x4 acc[4][4];
#pragma unroll
  for (int i = 0; i < 4; ++i)
#pragma unroll
    for (int j = 0; j < 4; ++j) acc[i][j] = fz;

  for (int k0 = 0; k0 < 1024; k0 += 32) {
    __syncthreads();
#pragma unroll
    for (int it = 0; it < 2; ++it) {
      int j = it * 256 + tid;
      int r = j >> 2, cl = j & 3;
      int c = cl ^ ((r >> 1) & 3);
      if (mbase + r < 400)
        g2l16(smA + j * 8, peb + (mbase + r) * 1024 + k0 + c * 8);
      else {
        uint4 zz = make_uint4(0, 0, 0, 0);
        *(uint4*)(smA + j * 8) = zz;
      }
    }
#pragma unroll
    for (int it = 0; it < 2; ++it) {
      int j = it * 256 + tid;
      int r = j >> 2, cl = j & 3;
      int c = cl ^ ((r >> 1) & 3);
      g2l16(smB + j * 8, Wpb + (nbase + r) * 1024 + k0 + c * 8);
    }
    __syncthreads();
    bf16x8 af[4], bfr[4];
#pragma unroll
    for (int mt = 0; mt < 4; ++mt) {
      int r = wm + mt * 16 + lrow;
      int ch = kg ^ ((r >> 1) & 3);
      af[mt] = *(const bf16x8*)(smA + r * 32 + ch * 8);
    }
#pragma unroll
    for (int nt = 0; nt < 4; ++nt) {
      int r = wn + nt * 16 + lrow;
      int ch = kg ^ ((r >> 1) & 3);
      bfr[nt] = *(const bf16x8*)(smB + r * 32 + ch * 8);
    }
#pragma unroll
    for (int nt = 0; nt < 4; ++nt)
#pragma unroll
      for (int mt = 0; mt < 4; ++mt)
        acc[mt][nt] = MFMA(af[mt], bfr[nt], acc[mt][nt]);
  }
#pragma unroll
  for (int mt = 0; mt < 4; ++mt)
#pragma unroll
    for (int rg = 0; rg < 4; ++rg) {
      int m = mbase + wm + mt * 16 + kg * 4 + rg;
      if (m < 400) {
#pragma unroll
        for (int nt = 0; nt < 4; ++nt) {
          int n = nbase + wn + nt * 16 + lrow;
          float base = acc[mt][nt][rg] + bp[n];
          posq[m * 1024 + n] = (bf16)(base + bq[n]);
          posk[m * 1024 + n] = (bf16)(base + bk[n]);
          posv[m * 1024 + n] = (bf16)(base + bv[n]);
        }
      }
    }
}

// ---------------- QKV projection: A fp32->bf16 staged via regs, BK=64 ----------------
// grid (100, 8, 3): m-tile fastest.
__global__ __launch_bounds__(256) void gemm_qkv(
    const float* __restrict__ Xq, const float* __restrict__ Xk, const float* __restrict__ Xv,
    const bf16* __restrict__ Wqb, const bf16* __restrict__ Wkb, const bf16* __restrict__ Wvb,
    const bf16* __restrict__ posq, const bf16* __restrict__ posk, const bf16* __restrict__ posv,
    bf16* __restrict__ qb, bf16* __restrict__ kbuf, bf16* __restrict__ vt) {
  __shared__ bf16 sm[16384];  // 32 KB: smA = [0,8192), smB = [8192,16384)
  bf16* smA = sm;
  bf16* smB = sm + 8192;
  const int z = blockIdx.z;
  const float* X = (z == 0) ? Xq : (z == 1) ? Xk : Xv;
  const bf16* W = (z == 0) ? Wqb : (z == 1) ? Wkb : Wvb;
  const bf16* posz = (z == 0) ? posq : (z == 1) ? posk : posv;
  const int mbase = blockIdx.x * 128;
  const int nbase = blockIdx.y * 128;
  const int tid = threadIdx.x;
  const int lane = tid & 63, w = tid >> 6;
  const int wm = (w >> 1) * 64, wn = (w & 1) * 64;
  const int lrow = lane & 15, kg = lane >> 4;
  const f32x4 fz = {0.f, 0.f, 0.f, 0.f};
  f32x4 acc[4][4];
#pragma unroll
  for (int i = 0; i < 4; ++i)
#pragma unroll
    for (int j = 0; j < 4; ++j) acc[i][j] = fz;

  f32x4 pre[4][2];
  // prologue: prefetch A k-slab 0
#pragma unroll
  for (int p = 0; p < 4; ++p) {
    int u = 2 * tid + 512 * p;
    int r = u >> 4, ucol = u & 15;
    const float* src = X + (size_t)(mbase + r) * 1024 + ucol * 4;
    pre[p][0] = *(const f32x4*)src;
    pre[p][1] = *(const f32x4*)(src + 4);
  }

  for (int k0 = 0; k0 < 1024; k0 += 64) {
    __syncthreads();
    // A: cvt regs -> LDS (swizzled 16B chunks: stored = ch ^ (r&7))
#pragma unroll
    for (int p = 0; p < 4; ++p) {
      int u = 2 * tid + 512 * p;
      int r = u >> 4, ch = (u & 15) >> 1;
      bf16x8 a;
      a[0] = (bf16)pre[p][0][0]; a[1] = (bf16)pre[p][0][1];
      a[2] = (bf16)pre[p][0][2]; a[3] = (bf16)pre[p][0][3];
      a[4] = (bf16)pre[p][1][0]; a[5] = (bf16)pre[p][1][1];
      a[6] = (bf16)pre[p][1][2]; a[7] = (bf16)pre[p][1][3];
      *(bf16x8*)(smA + r * 64 + (ch ^ (r & 7)) * 8) = a;
    }
    // B: async global->LDS
#pragma unroll
    for (int it = 0; it < 4; ++it) {
      int j = it * 256 + tid;
      int r = j >> 3, cl = j & 7;
      g2l16(smB + j * 8, W + (size_t)(nbase + r) * 1024 + k0 + (cl ^ (r & 7)) * 8);
    }
    // prefetch next A slab (overlaps with barrier drain + compute)
    if (k0 + 64 < 1024) {
#pragma unroll
      for (int p = 0; p < 4; ++p) {
        int u = 2 * tid + 512 * p;
        int r = u >> 4, ucol = u & 15;
        const float* src = X + (size_t)(mbase + r) * 1024 + k0 + 64 + ucol * 4;
        pre[p][0] = *(const f32x4*)src;
        pre[p][1] = *(const f32x4*)(src + 4);
      }
    }
    __syncthreads();
#pragma unroll
    for (int ks = 0; ks < 2; ++ks) {
      bf16x8 af[4], bfr[4];
#pragma unroll
      for (int mt = 0; mt < 4; ++mt) {
        int r = wm + mt * 16 + lrow;
        af[mt] = *(const bf16x8*)(smA + r * 64 + ((ks * 4 + kg) ^ (r & 7)) * 8);
      }
#pragma unroll
      for (int nt = 0; nt < 4; ++nt) {
        int r = wn + nt * 16 + lrow;
        bfr[nt] = *(const bf16x8*)(smB + r * 64 + ((ks * 4 + kg) ^ (r & 7)) * 8);
      }
#pragma unroll
      for (int nt = 0; nt < 4; ++nt)
#pragma unroll
        for (int mt = 0; mt < 4; ++mt)
          acc[mt][nt] = MFMA(af[mt], bfr[nt], acc[mt][nt]);
    }
  }

  if (z < 2) {
    bf16* dst = (z == 0) ? qb : kbuf;
#pragma unroll
    for (int mt = 0; mt < 4; ++mt)
#pragma unroll
      for (int rg = 0; rg < 4; ++rg) {
        int m = mbase + wm + mt * 16 + kg * 4 + rg;
        int bI = m / 400;
        int s = m - bI * 400;
#pragma unroll
        for (int nt = 0; nt < 4; ++nt) {
          int n = nbase + wn + nt * 16 + lrow;
          float v = acc[mt][nt][rg] + (float)posz[s * 1024 + n];
          int h = n >> 6, d = n & 63;
          dst[((size_t)(bI * 16 + h) * 400 + s) * 64 + d] = (bf16)v;
        }
      }
  } else {
    // V: transpose through LDS, store [b,h,d,s] with 16B-contiguous runs along s
    __syncthreads();
    bf16* T = sm;  // 128 n x 128 m, chunk-swizzled: stored_chk = chk ^ (n&15)
#pragma unroll
    for (int nt = 0; nt < 4; ++nt) {
      int n = wn + nt * 16 + lrow;
      int ng = nbase + n;
#pragma unroll
      for (int mt = 0; mt < 4; ++mt) {
        int m0 = wm + mt * 16 + kg * 4;
        bf16x4 v4;
#pragma unroll
        for (int rg = 0; rg < 4; ++rg) {
          int m = mbase + m0 + rg;
          int bI = m / 400;
          int s = m - bI * 400;
          v4[rg] = (bf16)(acc[mt][nt][rg] + (float)posz[s * 1024 + ng]);
        }
        int chk = m0 >> 3;
        int st = chk ^ (n & 15);
        *(bf16x4*)(T + n * 128 + st * 8 + (m0 & 7)) = v4;
      }
    }
    __syncthreads();
#pragma unroll
    for (int p = 0; p < 8; ++p) {
      int n = p * 16 + (tid >> 4);
      int chk = tid & 15;
      bf16x8 row = *(const bf16x8*)(T + n * 128 + (chk ^ (n & 15)) * 8);
      int ng = nbase + n;
      int h = ng >> 6, d = ng & 63;
      int m = mbase + chk * 8;
      int bI = m / 400;
      int s = m - bI * 400;
      *(bf16x8*)(vt + ((size_t)(bI * 16 + h) * 64 + d) * 400 + s) = row;
    }
  }
}

// ---------------- flash attention ----------------
__global__ __launch_bounds__(256) void attn_kernel(
    const bf16* __restrict__ qg, const bf16* __restrict__ kg_,
    const bf16* __restrict__ vg, const float* __restrict__ mask,
    bf16* __restrict__ ao) {
  __shared__ bf16 smQ[64 * 64];    // 8 KB
  __shared__ bf16 smK[128 * 64];   // 16 KB
  __shared__ bf16 smV[64 * 128];   // 16 KB (V^T: [d][s])
  __shared__ bf16 smP[64 * 128];   // 16 KB
  const int qt = blockIdx.x;       // 0..6
  const int bh = blockIdx.y;       // 0..511
  const int qbase = qt * 64;
  const int tid = threadIdx.x;
  const int lane = tid & 63;
  const int w = tid >> 6;
  const int lrow = lane & 15, kg = lane >> 4;
  const bf16* Qg = qg + bh * 25600;
  const bf16* Kg = kg_ + bh * 25600;
  const bf16* Vg = vg + bh * 25600;

#pragma unroll
  for (int it = 0; it < 2; ++it) {
    int j = it * 256 + tid;
    int r = j >> 3, cl = j & 7;
    int c = cl ^ (r & 7);
    int s = qbase + r;
    uint4 val = make_uint4(0, 0, 0, 0);
    if (s < 400) val = *(const uint4*)(Qg + s * 64 + c * 8);
    *(uint4*)(smQ + j * 8) = val;
  }

  const f32x4 fz = {0.f, 0.f, 0.f, 0.f};
  f32x4 o[4];
#pragma unroll
  for (int i = 0; i < 4; ++i) o[i] = fz;
  float m_run[4], l_run[4];
#pragma unroll
  for (int i = 0; i < 4; ++i) { m_run[i] = -1e30f; l_run[i] = 0.f; }

  for (int kt = 0; kt < 4; ++kt) {
#pragma unroll
    for (int it = 0; it < 4; ++it) {
      int j = it * 256 + tid;
      int r = j >> 3, cl = j & 7;
      int c = cl ^ (r & 7);
      int s = kt * 128 + r;
      uint4 val = make_uint4(0, 0, 0, 0);
      if (s < 400) val = *(const uint4*)(Kg + s * 64 + c * 8);
      *(uint4*)(smK + j * 8) = val;
    }
#pragma unroll
    for (int it = 0; it < 4; ++it) {
      int j = it * 256 + tid;
      int r = j >> 4, cl = j & 15;
      int c = cl ^ (r & 15);
      int s0 = kt * 128 + c * 8;
      uint4 val = make_uint4(0, 0, 0, 0);
      if (s0 < 400) val = *(const uint4*)(Vg + r * 400 + s0);
      *(uint4*)(smV + j * 8) = val;
    }
    __syncthreads();

    f32x4 sc[8];
#pragma unroll
    for (int nt = 0; nt < 8; ++nt) sc[nt] = fz;
#pragma unroll
    for (int ks = 0; ks < 2; ++ks) {
      int rq = w * 16 + lrow;
      int chq = (ks * 4 + kg) ^ (rq & 7);
      bf16x8 aq = *(const bf16x8*)(smQ + rq * 64 + chq * 8);
#pragma unroll
      for (int nt = 0; nt < 8; ++nt) {
        int rk = nt * 16 + lrow;
        int chk = (ks * 4 + kg) ^ (rk & 7);
        bf16x8 bk8 = *(const bf16x8*)(smK + rk * 64 + chk * 8);
        sc[nt] = MFMA(aq, bk8, sc[nt]);
      }
    }
    float alpha[4];
#pragma unroll
    for (int rg = 0; rg < 4; ++rg) {
      int qs = qbase + w * 16 + kg * 4 + rg;
      float rmax = -1e30f;
#pragma unroll
      for (int nt = 0; nt < 8; ++nt) {
        int ksi = kt * 128 + nt * 16 + lrow;
        float v = sc[nt][rg] * 0.125f;
        v += (ksi < 400) ? ((qs < 400) ? mask[qs * 400 + ksi] : 0.f) : -1e30f;
        sc[nt][rg] = v;
        rmax = fmaxf(rmax, v);
      }
#pragma unroll
      for (int off = 1; off < 16; off <<= 1)
        rmax = fmaxf(rmax, __shfl_xor(rmax, off, 64));
      float mn = fmaxf(m_run[rg], rmax);
      alpha[rg] = __expf(m_run[rg] - mn);
      m_run[rg] = mn;
      float rsum = 0.f;
#pragma unroll
      for (int nt = 0; nt < 8; ++nt) {
        float p = __expf(sc[nt][rg] - mn);
        sc[nt][rg] = p;
        rsum += p;
      }
#pragma unroll
      for (int off = 1; off < 16; off <<= 1)
        rsum += __shfl_xor(rsum, off, 64);
      l_run[rg] = l_run[rg] * alpha[rg] + rsum;
    }
#pragma unroll
    for (int nt2 = 0; nt2 < 4; ++nt2)
#pragma unroll
      for (int rg = 0; rg < 4; ++rg) o[nt2][rg] *= alpha[rg];
#pragma unroll
    for (int nt = 0; nt < 8; ++nt)
#pragma unroll
      for (int rg = 0; rg < 4; ++rg) {
        int row = w * 16 + kg * 4 + rg;
        int col = nt * 16 + lrow;
        int ch = (col >> 3) ^ (row & 15);
        smP[row * 128 + ch * 8 + (col & 7)] = (bf16)sc[nt][rg];
      }
    __syncthreads();
#pragma unroll
    for (int ks2 = 0; ks2 < 4; ++ks2) {
      int rp = w * 16 + lrow;
      int chp = (ks2 * 4 + kg) ^ (rp & 15);
      bf16x8 ap = *(const bf16x8*)(smP + rp * 128 + chp * 8);
#pragma unroll
      for (int nt2 = 0; nt2 < 4; ++nt2) {
        int rv = nt2 * 16 + lrow;
        int chv = (ks2 * 4 + kg) ^ (rv & 15);
        bf16x8 bv8 = *(const bf16x8*)(smV + rv * 128 + chv * 8);
        o[nt2] = MFMA(ap, bv8, o[nt2]);
      }
    }
    __syncthreads();
  }
  const int b = bh >> 4, h = bh & 15;
#pragma unroll
  for (int rg = 0; rg < 4; ++rg) {
    int qs = qbase + w * 16 + kg * 4 + rg;
    if (qs < 400) {
      float inv = 1.f / l_run[rg];
#pragma unroll
      for (int nt2 = 0; nt2 < 4; ++nt2) {
        ao[(b * 400 + qs) * 1024 + h * 64 + nt2 * 16 + lrow] =
            (bf16)(o[nt2][rg] * inv);
      }
    }
  }
}

// ---------------- output projection, BK=64 ----------------
__global__ __launch_bounds__(256) void gemm_out(
    const bf16* __restrict__ aop, const bf16* __restrict__ Wob,
    const float* __restrict__ bo, const float* __restrict__ gates,
    float* __restrict__ out) {
  __shared__ bf16 sm[16384];
  bf16* smA = sm;
  bf16* smB = sm + 8192;
  const int mbase = blockIdx.x * 128;
  const int nbase = blockIdx.y * 128;
  const int tid = threadIdx.x;
  const int lane = tid & 63, w = tid >> 6;
  const int wm = (w >> 1) * 64, wn = (w & 1) * 64;
  const int lrow = lane & 15, kg = lane >> 4;
  const float g = gates[0];
  const f32x4 fz = {0.f, 0.f, 0.f, 0.f};
  f32x4 acc[4][4];
#pragma unroll
  for (int i = 0; i < 4; ++i)
#pragma unroll
    for (int j = 0; j < 4; ++j) acc[i][j] = fz;

  for (int k0 = 0; k0 < 1024; k0 += 64) {
    __syncthreads();
#pragma unroll
    for (int it = 0; it < 4; ++it) {
      int j = it * 256 + tid;
      int r = j >> 3, cl = j & 7;
      g2l16(smA + j * 8, aop + (size_t)(mbase + r) * 1024 + k0 + (cl ^ (r & 7)) * 8);
    }
#pragma unroll
    for (int it = 0; it < 4; ++it) {
      int j = it * 256 + tid;
      int r = j >> 3, cl = j & 7;
      g2l16(smB + j * 8, Wob + (size_t)(nbase + r) * 1024 + k0 + (cl ^ (r & 7)) * 8);
    }
    __syncthreads();
#pragma unroll
    for (int ks = 0; ks < 2; ++ks) {
      bf16x8 af[4], bfr[4];
#pragma unroll
      for (int mt = 0; mt < 4; ++mt) {
        int r = wm + mt * 16 + lrow;
        af[mt] = *(const bf16x8*)(smA + r * 64 + ((ks * 4 + kg) ^ (r & 7)) * 8);
      }
#pragma unroll
      for (int nt = 0; nt < 4; ++nt) {
        int r = wn + nt * 16 + lrow;
        bfr[nt] = *(const bf16x8*)(smB + r * 64 + ((ks * 4 + kg) ^ (r & 7)) * 8);
      }
#pragma unroll
      for (int nt = 0; nt < 4; ++nt)
#pragma unroll
        for (int mt = 0; mt < 4; ++mt)
          acc[mt][nt] = MFMA(af[mt], bfr[nt], acc[mt][nt]);
    }
  }
#pragma unroll
  for (int mt = 0; mt < 4; ++mt)
#pragma unroll
    for (int rg = 0; rg < 4; ++rg) {
      int m = mbase + wm + mt * 16 + kg * 4 + rg;
#pragma unroll
      for (int nt = 0; nt < 4; ++nt) {
        int n = nbase + wn + nt * 16 + lrow;
        out[(size_t)m * 1024 + n] = (acc[mt][nt][rg] + bo[n]) * g;
      }
    }
}

extern "C" void kernel_launch(void* const* d_in, const int* in_sizes, int n_in,
                              void* d_out, int out_size, void* d_ws, size_t ws_size,
                              hipStream_t stream) {
  const float* query = (const float*)d_in[0];
  const float* key   = (const float*)d_in[1];
  const float* value = (const float*)d_in[2];
  const float* mask  = (const float*)d_in[3];
  const float* pe    = (const float*)d_in[4];
  const float* Wq = (const float*)d_in[5];
  const float* bq = (const float*)d_in[6];
  const float* Wk = (const float*)d_in[7];
  const float* bk = (const float*)d_in[8];
  const float* Wv = (const float*)d_in[9];
  const float* bv = (const float*)d_in[10];
  const float* Wp = (const float*)d_in[11];
  const float* bp = (const float*)d_in[12];
  const float* Wo = (const float*)d_in[13];
  const float* bo = (const float*)d_in[14];
  const float* gates = (const float*)d_in[15];
  float* out = (float*)d_out;

  char* base = (char*)d_ws;
  size_t off = 0;
  bf16* wq_b = (bf16*)(base + off); off += 2097152;
  bf16* wk_b = (bf16*)(base + off); off += 2097152;
  bf16* wv_b = (bf16*)(base + off); off += 2097152;
  bf16* wo_b = (bf16*)(base + off); off += 2097152;
  bf16* wp_b = (bf16*)(base + off); off += 2097152;
  bf16* pe_b = (bf16*)(base + off); off += 819200;
  bf16* posq = (bf16*)(base + off); off += 819200;
  bf16* posk = (bf16*)(base + off); off += 819200;
  bf16* posv = (bf16*)(base + off); off += 819200;
  bf16* qb = (bf16*)(base + off); off += 26214400;
  bf16* kb = (bf16*)(base + off); off += 26214400;
  bf16* vt = (bf16*)(base + off); off += 26214400;
  bf16* ao = (bf16*)(base + off); off += 26214400;
  (void)ws_size; (void)in_sizes; (void)n_in; (void)out_size;

  cvt_all<<<5520, 256, 0, stream>>>(Wq, Wk, Wv, Wo, Wp, pe,
                                    wq_b, wk_b, wv_b, wo_b, wp_b, pe_b);
  gemm_pos<<<dim3(8, 4), 256, 0, stream>>>(pe_b, wp_b, bp, bq, bk, bv,
                                           posq, posk, posv);
  gemm_qkv<<<dim3(100, 8, 3), 256, 0, stream>>>(query, key, value,
                                                wq_b, wk_b, wv_b,
                                                posq, posk, posv, qb, kb, vt);
  attn_kernel<<<dim3(7, 512), 256, 0, stream>>>(qb, kb, vt, mask, ao);
  gemm_out<<<dim3(100, 8), 256, 0, stream>>>(ao, wo_b, bo, gates, out);
}

// Round 4
// 559.752 us; speedup vs baseline: 1.2063x; 1.0152x over previous
//
#include <hip/hip_runtime.h>

typedef __bf16 bf16;
typedef __bf16 bf16x8 __attribute__((ext_vector_type(8)));
typedef __bf16 bf16x4 __attribute__((ext_vector_type(4)));
typedef float f32x4 __attribute__((ext_vector_type(4)));

#define MFMA(a, b, c) __builtin_amdgcn_mfma_f32_16x16x32_bf16(a, b, c, 0, 0, 0)

__device__ __forceinline__ void g2l16(void* lds, const void* g) {
  __builtin_amdgcn_global_load_lds(
      (const __attribute__((address_space(1))) void*)g,
      (__attribute__((address_space(3))) void*)lds, 16, 0, 0);
}

// ---------------- fp32 -> bf16 conversion (weights + pe only) ----------------
__global__ void cvt_all(
    const float* __restrict__ Wq, const float* __restrict__ Wk, const float* __restrict__ Wv,
    const float* __restrict__ Wo, const float* __restrict__ Wp, const float* __restrict__ pe,
    bf16* __restrict__ wqb, bf16* __restrict__ wkb, bf16* __restrict__ wvb,
    bf16* __restrict__ wob, bf16* __restrict__ wpb, bf16* __restrict__ peb) {
  int b = blockIdx.x;
  const float* s;
  bf16* d;
  int lb;
  if (b < 5120) {
    int t = b >> 10;
    lb = b & 1023;
    s = (t == 0) ? Wq : (t == 1) ? Wk : (t == 2) ? Wv : (t == 3) ? Wo : Wp;
    d = (t == 0) ? wqb : (t == 1) ? wkb : (t == 2) ? wvb : (t == 3) ? wob : wpb;
  } else {
    lb = b - 5120;
    s = pe;
    d = peb;
  }
  int i = lb * 256 + threadIdx.x;
  f32x4 v = *(const f32x4*)(s + i * 4);
  bf16x4 o;
  o[0] = (bf16)v[0]; o[1] = (bf16)v[1]; o[2] = (bf16)v[2]; o[3] = (bf16)v[3];
  *(bf16x4*)(d + i * 4) = o;
}

// ---------------- posq/k/v = bf16(pe @ Wp^T + bp + b{q,k,v}) ----------------
__global__ __launch_bounds__(256) void gemm_pos(
    const bf16* __restrict__ peb, const bf16* __restrict__ Wpb,
    const float* __restrict__ bp, const float* __restrict__ bq,
    const float* __restrict__ bk, const float* __restrict__ bv,
    bf16* __restrict__ posq, bf16* __restrict__ posk, bf16* __restrict__ posv) {
  __shared__ bf16 smA[128 * 32];
  __shared__ bf16 smB[128 * 32];
  const int mbase = blockIdx.y * 128;
  const int nbase = blockIdx.x * 128;
  const int tid = threadIdx.x;
  const int lane = tid & 63, w = tid >> 6;
  const int wm = (w >> 1) * 64, wn = (w & 1) * 64;
  const int lrow = lane & 15, kg = lane >> 4;
  const f32x4 fz = {0.f, 0.f, 0.f, 0.f};
  f32x4 acc[4][4];
#pragma unroll
  for (int i = 0; i < 4; ++i)
#pragma unroll
    for (int j = 0; j < 4; ++j) acc[i][j] = fz;

  for (int k0 = 0; k0 < 1024; k0 += 32) {
    __syncthreads();
#pragma unroll
    for (int it = 0; it < 2; ++it) {
      int j = it * 256 + tid;
      int r = j >> 2, cl = j & 3;
      int c = cl ^ ((r >> 1) & 3);
      if (mbase + r < 400)
        g2l16(smA + j * 8, peb + (mbase + r) * 1024 + k0 + c * 8);
      else {
        uint4 zz = make_uint4(0, 0, 0, 0);
        *(uint4*)(smA + j * 8) = zz;
      }
    }
#pragma unroll
    for (int it = 0; it < 2; ++it) {
      int j = it * 256 + tid;
      int r = j >> 2, cl = j & 3;
      int c = cl ^ ((r >> 1) & 3);
      g2l16(smB + j * 8, Wpb + (nbase + r) * 1024 + k0 + c * 8);
    }
    __syncthreads();
    bf16x8 af[4], bfr[4];
#pragma unroll
    for (int mt = 0; mt < 4; ++mt) {
      int r = wm + mt * 16 + lrow;
      int ch = kg ^ ((r >> 1) & 3);
      af[mt] = *(const bf16x8*)(smA + r * 32 + ch * 8);
    }
#pragma unroll
    for (int nt = 0; nt < 4; ++nt) {
      int r = wn + nt * 16 + lrow;
      int ch = kg ^ ((r >> 1) & 3);
      bfr[nt] = *(const bf16x8*)(smB + r * 32 + ch * 8);
    }
#pragma unroll
    for (int nt = 0; nt < 4; ++nt)
#pragma unroll
      for (int mt = 0; mt < 4; ++mt)
        acc[mt][nt] = MFMA(af[mt], bfr[nt], acc[mt][nt]);
  }
#pragma unroll
  for (int mt = 0; mt < 4; ++mt)
#pragma unroll
    for (int rg = 0; rg < 4; ++rg) {
      int m = mbase + wm + mt * 16 + kg * 4 + rg;
      if (m < 400) {
#pragma unroll
        for (int nt = 0; nt < 4; ++nt) {
          int n = nbase + wn + nt * 16 + lrow;
          float base = acc[mt][nt][rg] + bp[n];
          posq[m * 1024 + n] = (bf16)(base + bq[n]);
          posk[m * 1024 + n] = (bf16)(base + bk[n]);
          posv[m * 1024 + n] = (bf16)(base + bv[n]);
        }
      }
    }
}

// ---------------- QKV projection: A fp32->bf16 staged via regs, BK=64 ----------------
// grid (832, 3): lid = (m>>3)<<6 | n<<3 | (m&7) so the 8 n-blocks sharing an
// X m-strip are id-congruent mod 8 (same XCD) and within one 64-id window
// (co-dispatched) -> strip fetched once per chip, L2-served after.
__global__ __launch_bounds__(256) void gemm_qkv(
    const float* __restrict__ Xq, const float* __restrict__ Xk, const float* __restrict__ Xv,
    const bf16* __restrict__ Wqb, const bf16* __restrict__ Wkb, const bf16* __restrict__ Wvb,
    const bf16* __restrict__ posq, const bf16* __restrict__ posk, const bf16* __restrict__ posv,
    bf16* __restrict__ qb, bf16* __restrict__ kbuf, bf16* __restrict__ vt) {
  const int lid = blockIdx.x;
  const int mI = ((lid >> 6) << 3) + (lid & 7);
  const int nI = (lid >> 3) & 7;
  if (mI >= 100) return;
  __shared__ bf16 sm[16384];  // 32 KB: smA = [0,8192), smB = [8192,16384)
  bf16* smA = sm;
  bf16* smB = sm + 8192;
  const int z = blockIdx.y;
  const float* X = (z == 0) ? Xq : (z == 1) ? Xk : Xv;
  const bf16* W = (z == 0) ? Wqb : (z == 1) ? Wkb : Wvb;
  const bf16* posz = (z == 0) ? posq : (z == 1) ? posk : posv;
  const int mbase = mI * 128;
  const int nbase = nI * 128;
  const int tid = threadIdx.x;
  const int lane = tid & 63, w = tid >> 6;
  const int wm = (w >> 1) * 64, wn = (w & 1) * 64;
  const int lrow = lane & 15, kg = lane >> 4;
  const f32x4 fz = {0.f, 0.f, 0.f, 0.f};
  f32x4 acc[4][4];
#pragma unroll
  for (int i = 0; i < 4; ++i)
#pragma unroll
    for (int j = 0; j < 4; ++j) acc[i][j] = fz;

  f32x4 pre[4][2];
#pragma unroll
  for (int p = 0; p < 4; ++p) {
    int u = 2 * tid + 512 * p;
    int r = u >> 4, ucol = u & 15;
    const float* src = X + (size_t)(mbase + r) * 1024 + ucol * 4;
    pre[p][0] = *(const f32x4*)src;
    pre[p][1] = *(const f32x4*)(src + 4);
  }

  for (int k0 = 0; k0 < 1024; k0 += 64) {
    __syncthreads();
#pragma unroll
    for (int p = 0; p < 4; ++p) {
      int u = 2 * tid + 512 * p;
      int r = u >> 4, ch = (u & 15) >> 1;
      bf16x8 a;
      a[0] = (bf16)pre[p][0][0]; a[1] = (bf16)pre[p][0][1];
      a[2] = (bf16)pre[p][0][2]; a[3] = (bf16)pre[p][0][3];
      a[4] = (bf16)pre[p][1][0]; a[5] = (bf16)pre[p][1][1];
      a[6] = (bf16)pre[p][1][2]; a[7] = (bf16)pre[p][1][3];
      *(bf16x8*)(smA + r * 64 + (ch ^ (r & 7)) * 8) = a;
    }
#pragma unroll
    for (int it = 0; it < 4; ++it) {
      int j = it * 256 + tid;
      int r = j >> 3, cl = j & 7;
      g2l16(smB + j * 8, W + (size_t)(nbase + r) * 1024 + k0 + (cl ^ (r & 7)) * 8);
    }
    if (k0 + 64 < 1024) {
#pragma unroll
      for (int p = 0; p < 4; ++p) {
        int u = 2 * tid + 512 * p;
        int r = u >> 4, ucol = u & 15;
        const float* src = X + (size_t)(mbase + r) * 1024 + k0 + 64 + ucol * 4;
        pre[p][0] = *(const f32x4*)src;
        pre[p][1] = *(const f32x4*)(src + 4);
      }
    }
    __syncthreads();
#pragma unroll
    for (int ks = 0; ks < 2; ++ks) {
      bf16x8 af[4], bfr[4];
#pragma unroll
      for (int mt = 0; mt < 4; ++mt) {
        int r = wm + mt * 16 + lrow;
        af[mt] = *(const bf16x8*)(smA + r * 64 + ((ks * 4 + kg) ^ (r & 7)) * 8);
      }
#pragma unroll
      for (int nt = 0; nt < 4; ++nt) {
        int r = wn + nt * 16 + lrow;
        bfr[nt] = *(const bf16x8*)(smB + r * 64 + ((ks * 4 + kg) ^ (r & 7)) * 8);
      }
#pragma unroll
      for (int nt = 0; nt < 4; ++nt)
#pragma unroll
        for (int mt = 0; mt < 4; ++mt)
          acc[mt][nt] = MFMA(af[mt], bfr[nt], acc[mt][nt]);
    }
  }

  if (z < 2) {
    bf16* dst = (z == 0) ? qb : kbuf;
#pragma unroll
    for (int mt = 0; mt < 4; ++mt)
#pragma unroll
      for (int rg = 0; rg < 4; ++rg) {
        int m = mbase + wm + mt * 16 + kg * 4 + rg;
        int bI = m / 400;
        int s = m - bI * 400;
#pragma unroll
        for (int nt = 0; nt < 4; ++nt) {
          int n = nbase + wn + nt * 16 + lrow;
          float v = acc[mt][nt][rg] + (float)posz[s * 1024 + n];
          int h = n >> 6, d = n & 63;
          dst[((size_t)(bI * 16 + h) * 400 + s) * 64 + d] = (bf16)v;
        }
      }
  } else {
    __syncthreads();
    bf16* T = sm;  // 128 n x 128 m, chunk-swizzled
#pragma unroll
    for (int nt = 0; nt < 4; ++nt) {
      int n = wn + nt * 16 + lrow;
      int ng = nbase + n;
#pragma unroll
      for (int mt = 0; mt < 4; ++mt) {
        int m0 = wm + mt * 16 + kg * 4;
        bf16x4 v4;
#pragma unroll
        for (int rg = 0; rg < 4; ++rg) {
          int m = mbase + m0 + rg;
          int bI = m / 400;
          int s = m - bI * 400;
          v4[rg] = (bf16)(acc[mt][nt][rg] + (float)posz[s * 1024 + ng]);
        }
        int chk = m0 >> 3;
        int st = chk ^ (n & 15);
        *(bf16x4*)(T + n * 128 + st * 8 + (m0 & 7)) = v4;
      }
    }
    __syncthreads();
#pragma unroll
    for (int p = 0; p < 8; ++p) {
      int n = p * 16 + (tid >> 4);
      int chk = tid & 15;
      bf16x8 row = *(const bf16x8*)(T + n * 128 + (chk ^ (n & 15)) * 8);
      int ng = nbase + n;
      int h = ng >> 6, d = ng & 63;
      int m = mbase + chk * 8;
      int bI = m / 400;
      int s = m - bI * 400;
      *(bf16x8*)(vt + ((size_t)(bI * 16 + h) * 64 + d) * 400 + s) = row;
    }
  }
}

// ---------------- flash attention ----------------
// grid 4096: lid = (bh>>3)<<6 | qt<<3 | (bh&7); the 7 real q-tiles of one
// (b,h) share K/V (100 KB) on one XCD. qt==7 slot idles.
__global__ __launch_bounds__(256) void attn_kernel(
    const bf16* __restrict__ qg, const bf16* __restrict__ kg_,
    const bf16* __restrict__ vg, const float* __restrict__ mask,
    bf16* __restrict__ ao) {
  const int lid = blockIdx.x;
  const int qt = (lid >> 3) & 7;
  if (qt >= 7) return;
  const int bh = ((lid >> 6) << 3) + (lid & 7);
  __shared__ bf16 smQ[64 * 64];
  __shared__ bf16 smK[128 * 64];
  __shared__ bf16 smV[64 * 128];
  __shared__ bf16 smP[64 * 128];
  const int qbase = qt * 64;
  const int tid = threadIdx.x;
  const int lane = tid & 63;
  const int w = tid >> 6;
  const int lrow = lane & 15, kg = lane >> 4;
  const bf16* Qg = qg + bh * 25600;
  const bf16* Kg = kg_ + bh * 25600;
  const bf16* Vg = vg + bh * 25600;

#pragma unroll
  for (int it = 0; it < 2; ++it) {
    int j = it * 256 + tid;
    int r = j >> 3, cl = j & 7;
    int c = cl ^ (r & 7);
    int s = qbase + r;
    uint4 val = make_uint4(0, 0, 0, 0);
    if (s < 400) val = *(const uint4*)(Qg + s * 64 + c * 8);
    *(uint4*)(smQ + j * 8) = val;
  }

  const f32x4 fz = {0.f, 0.f, 0.f, 0.f};
  f32x4 o[4];
#pragma unroll
  for (int i = 0; i < 4; ++i) o[i] = fz;
  float m_run[4], l_run[4];
#pragma unroll
  for (int i = 0; i < 4; ++i) { m_run[i] = -1e30f; l_run[i] = 0.f; }

  for (int kt = 0; kt < 4; ++kt) {
#pragma unroll
    for (int it = 0; it < 4; ++it) {
      int j = it * 256 + tid;
      int r = j >> 3, cl = j & 7;
      int c = cl ^ (r & 7);
      int s = kt * 128 + r;
      uint4 val = make_uint4(0, 0, 0, 0);
      if (s < 400) val = *(const uint4*)(Kg + s * 64 + c * 8);
      *(uint4*)(smK + j * 8) = val;
    }
#pragma unroll
    for (int it = 0; it < 4; ++it) {
      int j = it * 256 + tid;
      int r = j >> 4, cl = j & 15;
      int c = cl ^ (r & 15);
      int s0 = kt * 128 + c * 8;
      uint4 val = make_uint4(0, 0, 0, 0);
      if (s0 < 400) val = *(const uint4*)(Vg + r * 400 + s0);
      *(uint4*)(smV + j * 8) = val;
    }
    __syncthreads();

    f32x4 sc[8];
#pragma unroll
    for (int nt = 0; nt < 8; ++nt) sc[nt] = fz;
#pragma unroll
    for (int ks = 0; ks < 2; ++ks) {
      int rq = w * 16 + lrow;
      int chq = (ks * 4 + kg) ^ (rq & 7);
      bf16x8 aq = *(const bf16x8*)(smQ + rq * 64 + chq * 8);
#pragma unroll
      for (int nt = 0; nt < 8; ++nt) {
        int rk = nt * 16 + lrow;
        int chk = (ks * 4 + kg) ^ (rk & 7);
        bf16x8 bk8 = *(const bf16x8*)(smK + rk * 64 + chk * 8);
        sc[nt] = MFMA(aq, bk8, sc[nt]);
      }
    }
    float alpha[4];
#pragma unroll
    for (int rg = 0; rg < 4; ++rg) {
      int qs = qbase + w * 16 + kg * 4 + rg;
      float rmax = -1e30f;
#pragma unroll
      for (int nt = 0; nt < 8; ++nt) {
        int ksi = kt * 128 + nt * 16 + lrow;
        float v = sc[nt][rg] * 0.125f;
        v += (ksi < 400) ? ((qs < 400) ? mask[qs * 400 + ksi] : 0.f) : -1e30f;
        sc[nt][rg] = v;
        rmax = fmaxf(rmax, v);
      }
#pragma unroll
      for (int off = 1; off < 16; off <<= 1)
        rmax = fmaxf(rmax, __shfl_xor(rmax, off, 64));
      float mn = fmaxf(m_run[rg], rmax);
      alpha[rg] = __expf(m_run[rg] - mn);
      m_run[rg] = mn;
      float rsum = 0.f;
#pragma unroll
      for (int nt = 0; nt < 8; ++nt) {
        float p = __expf(sc[nt][rg] - mn);
        sc[nt][rg] = p;
        rsum += p;
      }
#pragma unroll
      for (int off = 1; off < 16; off <<= 1)
        rsum += __shfl_xor(rsum, off, 64);
      l_run[rg] = l_run[rg] * alpha[rg] + rsum;
    }
#pragma unroll
    for (int nt2 = 0; nt2 < 4; ++nt2)
#pragma unroll
      for (int rg = 0; rg < 4; ++rg) o[nt2][rg] *= alpha[rg];
#pragma unroll
    for (int nt = 0; nt < 8; ++nt)
#pragma unroll
      for (int rg = 0; rg < 4; ++rg) {
        int row = w * 16 + kg * 4 + rg;
        int col = nt * 16 + lrow;
        int ch = (col >> 3) ^ (row & 15);
        smP[row * 128 + ch * 8 + (col & 7)] = (bf16)sc[nt][rg];
      }
    __syncthreads();
#pragma unroll
    for (int ks2 = 0; ks2 < 4; ++ks2) {
      int rp = w * 16 + lrow;
      int chp = (ks2 * 4 + kg) ^ (rp & 15);
      bf16x8 ap = *(const bf16x8*)(smP + rp * 128 + chp * 8);
#pragma unroll
      for (int nt2 = 0; nt2 < 4; ++nt2) {
        int rv = nt2 * 16 + lrow;
        int chv = (ks2 * 4 + kg) ^ (rv & 15);
        bf16x8 bv8 = *(const bf16x8*)(smV + rv * 128 + chv * 8);
        o[nt2] = MFMA(ap, bv8, o[nt2]);
      }
    }
    __syncthreads();
  }
  const int b = bh >> 4, h = bh & 15;
#pragma unroll
  for (int rg = 0; rg < 4; ++rg) {
    int qs = qbase + w * 16 + kg * 4 + rg;
    if (qs < 400) {
      float inv = 1.f / l_run[rg];
#pragma unroll
      for (int nt2 = 0; nt2 < 4; ++nt2) {
        ao[(b * 400 + qs) * 1024 + h * 64 + nt2 * 16 + lrow] =
            (bf16)(o[nt2][rg] * inv);
      }
    }
  }
}

// ---------------- output projection, BK=64, XCD-swizzled ----------------
__global__ __launch_bounds__(256) void gemm_out(
    const bf16* __restrict__ aop, const bf16* __restrict__ Wob,
    const float* __restrict__ bo, const float* __restrict__ gates,
    float* __restrict__ out) {
  const int lid = blockIdx.x;
  const int mI = ((lid >> 6) << 3) + (lid & 7);
  const int nI = (lid >> 3) & 7;
  if (mI >= 100) return;
  __shared__ bf16 sm[16384];
  bf16* smA = sm;
  bf16* smB = sm + 8192;
  const int mbase = mI * 128;
  const int nbase = nI * 128;
  const int tid = threadIdx.x;
  const int lane = tid & 63, w = tid >> 6;
  const int wm = (w >> 1) * 64, wn = (w & 1) * 64;
  const int lrow = lane & 15, kg = lane >> 4;
  const float g = gates[0];
  const f32x4 fz = {0.f, 0.f, 0.f, 0.f};
  f32x4 acc[4][4];
#pragma unroll
  for (int i = 0; i < 4; ++i)
#pragma unroll
    for (int j = 0; j < 4; ++j) acc[i][j] = fz;

  for (int k0 = 0; k0 < 1024; k0 += 64) {
    __syncthreads();
#pragma unroll
    for (int it = 0; it < 4; ++it) {
      int j = it * 256 + tid;
      int r = j >> 3, cl = j & 7;
      g2l16(smA + j * 8, aop + (size_t)(mbase + r) * 1024 + k0 + (cl ^ (r & 7)) * 8);
    }
#pragma unroll
    for (int it = 0; it < 4; ++it) {
      int j = it * 256 + tid;
      int r = j >> 3, cl = j & 7;
      g2l16(smB + j * 8, Wob + (size_t)(nbase + r) * 1024 + k0 + (cl ^ (r & 7)) * 8);
    }
    __syncthreads();
#pragma unroll
    for (int ks = 0; ks < 2; ++ks) {
      bf16x8 af[4], bfr[4];
#pragma unroll
      for (int mt = 0; mt < 4; ++mt) {
        int r = wm + mt * 16 + lrow;
        af[mt] = *(const bf16x8*)(smA + r * 64 + ((ks * 4 + kg) ^ (r & 7)) * 8);
      }
#pragma unroll
      for (int nt = 0; nt < 4; ++nt) {
        int r = wn + nt * 16 + lrow;
        bfr[nt] = *(const bf16x8*)(smB + r * 64 + ((ks * 4 + kg) ^ (r & 7)) * 8);
      }
#pragma unroll
      for (int nt = 0; nt < 4; ++nt)
#pragma unroll
        for (int mt = 0; mt < 4; ++mt)
          acc[mt][nt] = MFMA(af[mt], bfr[nt], acc[mt][nt]);
    }
  }
#pragma unroll
  for (int mt = 0; mt < 4; ++mt)
#pragma unroll
    for (int rg = 0; rg < 4; ++rg) {
      int m = mbase + wm + mt * 16 + kg * 4 + rg;
#pragma unroll
      for (int nt = 0; nt < 4; ++nt) {
        int n = nbase + wn + nt * 16 + lrow;
        out[(size_t)m * 1024 + n] = (acc[mt][nt][rg] + bo[n]) * g;
      }
    }
}

extern "C" void kernel_launch(void* const* d_in, const int* in_sizes, int n_in,
                              void* d_out, int out_size, void* d_ws, size_t ws_size,
                              hipStream_t stream) {
  const float* query = (const float*)d_in[0];
  const float* key   = (const float*)d_in[1];
  const float* value = (const float*)d_in[2];
  const float* mask  = (const float*)d_in[3];
  const float* pe    = (const float*)d_in[4];
  const float* Wq = (const float*)d_in[5];
  const float* bq = (const float*)d_in[6];
  const float* Wk = (const float*)d_in[7];
  const float* bk = (const float*)d_in[8];
  const float* Wv = (const float*)d_in[9];
  const float* bv = (const float*)d_in[10];
  const float* Wp = (const float*)d_in[11];
  const float* bp = (const float*)d_in[12];
  const float* Wo = (const float*)d_in[13];
  const float* bo = (const float*)d_in[14];
  const float* gates = (const float*)d_in[15];
  float* out = (float*)d_out;

  char* base = (char*)d_ws;
  size_t off = 0;
  bf16* wq_b = (bf16*)(base + off); off += 2097152;
  bf16* wk_b = (bf16*)(base + off); off += 2097152;
  bf16* wv_b = (bf16*)(base + off); off += 2097152;
  bf16* wo_b = (bf16*)(base + off); off += 2097152;
  bf16* wp_b = (bf16*)(base + off); off += 2097152;
  bf16* pe_b = (bf16*)(base + off); off += 819200;
  bf16* posq = (bf16*)(base + off); off += 819200;
  bf16* posk = (bf16*)(base + off); off += 819200;
  bf16* posv = (bf16*)(base + off); off += 819200;
  bf16* qb = (bf16*)(base + off); off += 26214400;
  bf16* kb = (bf16*)(base + off); off += 26214400;
  bf16* vt = (bf16*)(base + off); off += 26214400;
  bf16* ao = (bf16*)(base + off); off += 26214400;
  (void)ws_size; (void)in_sizes; (void)n_in; (void)out_size;

  cvt_all<<<5520, 256, 0, stream>>>(Wq, Wk, Wv, Wo, Wp, pe,
                                    wq_b, wk_b, wv_b, wo_b, wp_b, pe_b);
  gemm_pos<<<dim3(8, 4), 256, 0, stream>>>(pe_b, wp_b, bp, bq, bk, bv,
                                           posq, posk, posv);
  gemm_qkv<<<dim3(832, 3), 256, 0, stream>>>(query, key, value,
                                             wq_b, wk_b, wv_b,
                                             posq, posk, posv, qb, kb, vt);
  attn_kernel<<<4096, 256, 0, stream>>>(qb, kb, vt, mask, ao);
  gemm_out<<<832, 256, 0, stream>>>(ao, wo_b, bo, gates, out);
}

// Round 5
// 556.609 us; speedup vs baseline: 1.2132x; 1.0056x over previous
//
#include <hip/hip_runtime.h>

typedef __bf16 bf16;
typedef __bf16 bf16x8 __attribute__((ext_vector_type(8)));
typedef __bf16 bf16x4 __attribute__((ext_vector_type(4)));
typedef float f32x4 __attribute__((ext_vector_type(4)));

#define MFMA(a, b, c) __builtin_amdgcn_mfma_f32_16x16x32_bf16(a, b, c, 0, 0, 0)

__device__ __forceinline__ void g2l16(void* lds, const void* g) {
  __builtin_amdgcn_global_load_lds(
      (const __attribute__((address_space(1))) void*)g,
      (__attribute__((address_space(3))) void*)lds, 16, 0, 0);
}

// ---------------- fp32 -> bf16 conversion (weights + pe only) ----------------
__global__ void cvt_all(
    const float* __restrict__ Wq, const float* __restrict__ Wk, const float* __restrict__ Wv,
    const float* __restrict__ Wo, const float* __restrict__ Wp, const float* __restrict__ pe,
    bf16* __restrict__ wqb, bf16* __restrict__ wkb, bf16* __restrict__ wvb,
    bf16* __restrict__ wob, bf16* __restrict__ wpb, bf16* __restrict__ peb) {
  int b = blockIdx.x;
  const float* s;
  bf16* d;
  int lb;
  if (b < 5120) {
    int t = b >> 10;
    lb = b & 1023;
    s = (t == 0) ? Wq : (t == 1) ? Wk : (t == 2) ? Wv : (t == 3) ? Wo : Wp;
    d = (t == 0) ? wqb : (t == 1) ? wkb : (t == 2) ? wvb : (t == 3) ? wob : wpb;
  } else {
    lb = b - 5120;
    s = pe;
    d = peb;
  }
  int i = lb * 256 + threadIdx.x;
  f32x4 v = *(const f32x4*)(s + i * 4);
  bf16x4 o;
  o[0] = (bf16)v[0]; o[1] = (bf16)v[1]; o[2] = (bf16)v[2]; o[3] = (bf16)v[3];
  *(bf16x4*)(d + i * 4) = o;
}

// ---------------- posq/k/v = bf16(pe @ Wp^T + bp + b{q,k,v}) ----------------
__global__ __launch_bounds__(256) void gemm_pos(
    const bf16* __restrict__ peb, const bf16* __restrict__ Wpb,
    const float* __restrict__ bp, const float* __restrict__ bq,
    const float* __restrict__ bk, const float* __restrict__ bv,
    bf16* __restrict__ posq, bf16* __restrict__ posk, bf16* __restrict__ posv) {
  __shared__ bf16 smA[128 * 32];
  __shared__ bf16 smB[128 * 32];
  const int mbase = blockIdx.y * 128;
  const int nbase = blockIdx.x * 128;
  const int tid = threadIdx.x;
  const int lane = tid & 63, w = tid >> 6;
  const int wm = (w >> 1) * 64, wn = (w & 1) * 64;
  const int lrow = lane & 15, kg = lane >> 4;
  const f32x4 fz = {0.f, 0.f, 0.f, 0.f};
  f32x4 acc[4][4];
#pragma unroll
  for (int i = 0; i < 4; ++i)
#pragma unroll
    for (int j = 0; j < 4; ++j) acc[i][j] = fz;

  for (int k0 = 0; k0 < 1024; k0 += 32) {
    __syncthreads();
#pragma unroll
    for (int it = 0; it < 2; ++it) {
      int j = it * 256 + tid;
      int r = j >> 2, cl = j & 3;
      int c = cl ^ ((r >> 1) & 3);
      if (mbase + r < 400)
        g2l16(smA + j * 8, peb + (mbase + r) * 1024 + k0 + c * 8);
      else {
        uint4 zz = make_uint4(0, 0, 0, 0);
        *(uint4*)(smA + j * 8) = zz;
      }
    }
#pragma unroll
    for (int it = 0; it < 2; ++it) {
      int j = it * 256 + tid;
      int r = j >> 2, cl = j & 3;
      int c = cl ^ ((r >> 1) & 3);
      g2l16(smB + j * 8, Wpb + (nbase + r) * 1024 + k0 + c * 8);
    }
    __syncthreads();
    bf16x8 af[4], bfr[4];
#pragma unroll
    for (int mt = 0; mt < 4; ++mt) {
      int r = wm + mt * 16 + lrow;
      int ch = kg ^ ((r >> 1) & 3);
      af[mt] = *(const bf16x8*)(smA + r * 32 + ch * 8);
    }
#pragma unroll
    for (int nt = 0; nt < 4; ++nt) {
      int r = wn + nt * 16 + lrow;
      int ch = kg ^ ((r >> 1) & 3);
      bfr[nt] = *(const bf16x8*)(smB + r * 32 + ch * 8);
    }
#pragma unroll
    for (int nt = 0; nt < 4; ++nt)
#pragma unroll
      for (int mt = 0; mt < 4; ++mt)
        acc[mt][nt] = MFMA(af[mt], bfr[nt], acc[mt][nt]);
  }
#pragma unroll
  for (int mt = 0; mt < 4; ++mt)
#pragma unroll
    for (int rg = 0; rg < 4; ++rg) {
      int m = mbase + wm + mt * 16 + kg * 4 + rg;
      if (m < 400) {
#pragma unroll
        for (int nt = 0; nt < 4; ++nt) {
          int n = nbase + wn + nt * 16 + lrow;
          float base = acc[mt][nt][rg] + bp[n];
          posq[m * 1024 + n] = (bf16)(base + bq[n]);
          posk[m * 1024 + n] = (bf16)(base + bk[n]);
          posv[m * 1024 + n] = (bf16)(base + bv[n]);
        }
      }
    }
}

// ---------------- QKV projection: 512 threads, 8 waves of 32x64 sub-tiles ----------------
// grid (832, 3): lid = (m>>3)<<6 | n<<3 | (m&7) — XCD co-residency for X strips.
__global__ __launch_bounds__(512, 4) void gemm_qkv(
    const float* __restrict__ Xq, const float* __restrict__ Xk, const float* __restrict__ Xv,
    const bf16* __restrict__ Wqb, const bf16* __restrict__ Wkb, const bf16* __restrict__ Wvb,
    const bf16* __restrict__ posq, const bf16* __restrict__ posk, const bf16* __restrict__ posv,
    bf16* __restrict__ qb, bf16* __restrict__ kbuf, bf16* __restrict__ vt) {
  const int lid = blockIdx.x;
  const int mI = ((lid >> 6) << 3) + (lid & 7);
  const int nI = (lid >> 3) & 7;
  if (mI >= 100) return;
  __shared__ bf16 sm[16384];  // 32 KB: smA [0,8192), smB [8192,16384)
  bf16* smA = sm;
  bf16* smB = sm + 8192;
  const int z = blockIdx.y;
  const float* X = (z == 0) ? Xq : (z == 1) ? Xk : Xv;
  const bf16* W = (z == 0) ? Wqb : (z == 1) ? Wkb : Wvb;
  const bf16* posz = (z == 0) ? posq : (z == 1) ? posk : posv;
  const int mbase = mI * 128;
  const int nbase = nI * 128;
  const int tid = threadIdx.x;
  const int lane = tid & 63, w = tid >> 6;     // w < 8
  const int wm = (w >> 1) * 32, wn = (w & 1) * 64;
  const int lrow = lane & 15, kg = lane >> 4;
  const f32x4 fz = {0.f, 0.f, 0.f, 0.f};
  f32x4 acc[2][4];
#pragma unroll
  for (int i = 0; i < 2; ++i)
#pragma unroll
    for (int j = 0; j < 4; ++j) acc[i][j] = fz;

  f32x4 pre[2][2];
#pragma unroll
  for (int p = 0; p < 2; ++p) {
    int u = 2 * tid + 1024 * p;
    int r = u >> 4, ucol = u & 15;
    const float* src = X + (size_t)(mbase + r) * 1024 + ucol * 4;
    pre[p][0] = *(const f32x4*)src;
    pre[p][1] = *(const f32x4*)(src + 4);
  }

  for (int k0 = 0; k0 < 1024; k0 += 64) {
    __syncthreads();
#pragma unroll
    for (int p = 0; p < 2; ++p) {
      int u = 2 * tid + 1024 * p;
      int r = u >> 4, ch = (u & 15) >> 1;
      bf16x8 a;
      a[0] = (bf16)pre[p][0][0]; a[1] = (bf16)pre[p][0][1];
      a[2] = (bf16)pre[p][0][2]; a[3] = (bf16)pre[p][0][3];
      a[4] = (bf16)pre[p][1][0]; a[5] = (bf16)pre[p][1][1];
      a[6] = (bf16)pre[p][1][2]; a[7] = (bf16)pre[p][1][3];
      *(bf16x8*)(smA + r * 64 + (ch ^ (r & 7)) * 8) = a;
    }
#pragma unroll
    for (int it = 0; it < 2; ++it) {
      int j = it * 512 + tid;
      int r = j >> 3, cl = j & 7;
      g2l16(smB + j * 8, W + (size_t)(nbase + r) * 1024 + k0 + (cl ^ (r & 7)) * 8);
    }
    if (k0 + 64 < 1024) {
#pragma unroll
      for (int p = 0; p < 2; ++p) {
        int u = 2 * tid + 1024 * p;
        int r = u >> 4, ucol = u & 15;
        const float* src = X + (size_t)(mbase + r) * 1024 + k0 + 64 + ucol * 4;
        pre[p][0] = *(const f32x4*)src;
        pre[p][1] = *(const f32x4*)(src + 4);
      }
    }
    __syncthreads();
#pragma unroll
    for (int ks = 0; ks < 2; ++ks) {
      bf16x8 af[2], bfr[4];
#pragma unroll
      for (int mt = 0; mt < 2; ++mt) {
        int r = wm + mt * 16 + lrow;
        af[mt] = *(const bf16x8*)(smA + r * 64 + ((ks * 4 + kg) ^ (r & 7)) * 8);
      }
#pragma unroll
      for (int nt = 0; nt < 4; ++nt) {
        int r = wn + nt * 16 + lrow;
        bfr[nt] = *(const bf16x8*)(smB + r * 64 + ((ks * 4 + kg) ^ (r & 7)) * 8);
      }
#pragma unroll
      for (int nt = 0; nt < 4; ++nt)
#pragma unroll
        for (int mt = 0; mt < 2; ++mt)
          acc[mt][nt] = MFMA(af[mt], bfr[nt], acc[mt][nt]);
    }
  }

  if (z < 2) {
    bf16* dst = (z == 0) ? qb : kbuf;
#pragma unroll
    for (int mt = 0; mt < 2; ++mt)
#pragma unroll
      for (int rg = 0; rg < 4; ++rg) {
        int m = mbase + wm + mt * 16 + kg * 4 + rg;
        int bI = m / 400;
        int s = m - bI * 400;
#pragma unroll
        for (int nt = 0; nt < 4; ++nt) {
          int n = nbase + wn + nt * 16 + lrow;
          float v = acc[mt][nt][rg] + (float)posz[s * 1024 + n];
          int h = n >> 6, d = n & 63;
          dst[((size_t)(bI * 16 + h) * 400 + s) * 64 + d] = (bf16)v;
        }
      }
  } else {
    __syncthreads();
    bf16* T = sm;  // 128 n x 128 m bf16 = 32 KB, chunk-swizzled
#pragma unroll
    for (int nt = 0; nt < 4; ++nt) {
      int n = wn + nt * 16 + lrow;
      int ng = nbase + n;
#pragma unroll
      for (int mt = 0; mt < 2; ++mt) {
        int m0 = wm + mt * 16 + kg * 4;
        bf16x4 v4;
#pragma unroll
        for (int rg = 0; rg < 4; ++rg) {
          int m = mbase + m0 + rg;
          int bI = m / 400;
          int s = m - bI * 400;
          v4[rg] = (bf16)(acc[mt][nt][rg] + (float)posz[s * 1024 + ng]);
        }
        int chk = m0 >> 3;
        int st = chk ^ (n & 15);
        *(bf16x4*)(T + n * 128 + st * 8 + (m0 & 7)) = v4;
      }
    }
    __syncthreads();
#pragma unroll
    for (int p = 0; p < 4; ++p) {
      int n = p * 32 + (tid >> 4);
      int chk = tid & 15;
      bf16x8 row = *(const bf16x8*)(T + n * 128 + (chk ^ (n & 15)) * 8);
      int ng = nbase + n;
      int h = ng >> 6, d = ng & 63;
      int m = mbase + chk * 8;
      int bI = m / 400;
      int s = m - bI * 400;
      *(bf16x8*)(vt + ((size_t)(bI * 16 + h) * 64 + d) * 400 + s) = row;
    }
  }
}

// ---------------- flash attention: 512 threads, 128-row Q tile ----------------
// grid 2048: lid = (bh>>3)<<5 | qt<<3 | (bh&7); 4 q-tiles of one (b,h) share
// K/V on one XCD.
__global__ __launch_bounds__(512, 4) void attn_kernel(
    const bf16* __restrict__ qg, const bf16* __restrict__ kg_,
    const bf16* __restrict__ vg, const float* __restrict__ mask,
    bf16* __restrict__ ao) {
  const int lid = blockIdx.x;
  const int qt = (lid >> 3) & 3;
  const int bh = ((lid >> 5) << 3) + (lid & 7);
  __shared__ bf16 smQ[128 * 64];   // 16 KB
  __shared__ bf16 smK[128 * 64];   // 16 KB
  __shared__ bf16 smV[64 * 128];   // 16 KB (V^T: [d][s])
  __shared__ bf16 smP[128 * 128];  // 32 KB
  const int qbase = qt * 128;
  const int tid = threadIdx.x;
  const int lane = tid & 63;
  const int w = tid >> 6;          // w < 8
  const int lrow = lane & 15, kg = lane >> 4;
  const bf16* Qg = qg + bh * 25600;
  const bf16* Kg = kg_ + bh * 25600;
  const bf16* Vg = vg + bh * 25600;

#pragma unroll
  for (int it = 0; it < 2; ++it) {
    int j = it * 512 + tid;
    int r = j >> 3, cl = j & 7;
    int c = cl ^ (r & 7);
    int s = qbase + r;
    uint4 val = make_uint4(0, 0, 0, 0);
    if (s < 400) val = *(const uint4*)(Qg + s * 64 + c * 8);
    *(uint4*)(smQ + j * 8) = val;
  }

  const f32x4 fz = {0.f, 0.f, 0.f, 0.f};
  f32x4 o[4];
#pragma unroll
  for (int i = 0; i < 4; ++i) o[i] = fz;
  float m_run[4], l_run[4];
#pragma unroll
  for (int i = 0; i < 4; ++i) { m_run[i] = -1e30f; l_run[i] = 0.f; }

  for (int kt = 0; kt < 4; ++kt) {
#pragma unroll
    for (int it = 0; it < 2; ++it) {
      int j = it * 512 + tid;
      int r = j >> 3, cl = j & 7;
      int c = cl ^ (r & 7);
      int s = kt * 128 + r;
      uint4 val = make_uint4(0, 0, 0, 0);
      if (s < 400) val = *(const uint4*)(Kg + s * 64 + c * 8);
      *(uint4*)(smK + j * 8) = val;
    }
#pragma unroll
    for (int it = 0; it < 2; ++it) {
      int j = it * 512 + tid;
      int r = j >> 4, cl = j & 15;
      int c = cl ^ (r & 15);
      int s0 = kt * 128 + c * 8;
      uint4 val = make_uint4(0, 0, 0, 0);
      if (s0 < 400) val = *(const uint4*)(Vg + r * 400 + s0);
      *(uint4*)(smV + j * 8) = val;
    }
    __syncthreads();

    f32x4 sc[8];
#pragma unroll
    for (int nt = 0; nt < 8; ++nt) sc[nt] = fz;
#pragma unroll
    for (int ks = 0; ks < 2; ++ks) {
      int rq = w * 16 + lrow;
      int chq = (ks * 4 + kg) ^ (rq & 7);
      bf16x8 aq = *(const bf16x8*)(smQ + rq * 64 + chq * 8);
#pragma unroll
      for (int nt = 0; nt < 8; ++nt) {
        int rk = nt * 16 + lrow;
        int chk = (ks * 4 + kg) ^ (rk & 7);
        bf16x8 bk8 = *(const bf16x8*)(smK + rk * 64 + chk * 8);
        sc[nt] = MFMA(aq, bk8, sc[nt]);
      }
    }
    float alpha[4];
#pragma unroll
    for (int rg = 0; rg < 4; ++rg) {
      int qs = qbase + w * 16 + kg * 4 + rg;
      float rmax = -1e30f;
#pragma unroll
      for (int nt = 0; nt < 8; ++nt) {
        int ksi = kt * 128 + nt * 16 + lrow;
        float v = sc[nt][rg] * 0.125f;
        v += (ksi < 400) ? ((qs < 400) ? mask[qs * 400 + ksi] : 0.f) : -1e30f;
        sc[nt][rg] = v;
        rmax = fmaxf(rmax, v);
      }
#pragma unroll
      for (int off = 1; off < 16; off <<= 1)
        rmax = fmaxf(rmax, __shfl_xor(rmax, off, 64));
      float mn = fmaxf(m_run[rg], rmax);
      alpha[rg] = __expf(m_run[rg] - mn);
      m_run[rg] = mn;
      float rsum = 0.f;
#pragma unroll
      for (int nt = 0; nt < 8; ++nt) {
        float p = __expf(sc[nt][rg] - mn);
        sc[nt][rg] = p;
        rsum += p;
      }
#pragma unroll
      for (int off = 1; off < 16; off <<= 1)
        rsum += __shfl_xor(rsum, off, 64);
      l_run[rg] = l_run[rg] * alpha[rg] + rsum;
    }
#pragma unroll
    for (int nt2 = 0; nt2 < 4; ++nt2)
#pragma unroll
      for (int rg = 0; rg < 4; ++rg) o[nt2][rg] *= alpha[rg];
#pragma unroll
    for (int nt = 0; nt < 8; ++nt)
#pragma unroll
      for (int rg = 0; rg < 4; ++rg) {
        int row = w * 16 + kg * 4 + rg;
        int col = nt * 16 + lrow;
        int ch = (col >> 3) ^ (row & 15);
        smP[row * 128 + ch * 8 + (col & 7)] = (bf16)sc[nt][rg];
      }
    __syncthreads();
#pragma unroll
    for (int ks2 = 0; ks2 < 4; ++ks2) {
      int rp = w * 16 + lrow;
      int chp = (ks2 * 4 + kg) ^ (rp & 15);
      bf16x8 ap = *(const bf16x8*)(smP + rp * 128 + chp * 8);
#pragma unroll
      for (int nt2 = 0; nt2 < 4; ++nt2) {
        int rv = nt2 * 16 + lrow;
        int chv = (ks2 * 4 + kg) ^ (rv & 15);
        bf16x8 bv8 = *(const bf16x8*)(smV + rv * 128 + chv * 8);
        o[nt2] = MFMA(ap, bv8, o[nt2]);
      }
    }
    __syncthreads();
  }
  const int b = bh >> 4, h = bh & 15;
#pragma unroll
  for (int rg = 0; rg < 4; ++rg) {
    int qs = qbase + w * 16 + kg * 4 + rg;
    if (qs < 400) {
      float inv = 1.f / l_run[rg];
#pragma unroll
      for (int nt2 = 0; nt2 < 4; ++nt2) {
        ao[(b * 400 + qs) * 1024 + h * 64 + nt2 * 16 + lrow] =
            (bf16)(o[nt2][rg] * inv);
      }
    }
  }
}

// ---------------- output projection: 512 threads, BK=64, XCD-swizzled ----------------
__global__ __launch_bounds__(512, 4) void gemm_out(
    const bf16* __restrict__ aop, const bf16* __restrict__ Wob,
    const float* __restrict__ bo, const float* __restrict__ gates,
    float* __restrict__ out) {
  const int lid = blockIdx.x;
  const int mI = ((lid >> 6) << 3) + (lid & 7);
  const int nI = (lid >> 3) & 7;
  if (mI >= 100) return;
  __shared__ bf16 sm[16384];
  bf16* smA = sm;
  bf16* smB = sm + 8192;
  const int mbase = mI * 128;
  const int nbase = nI * 128;
  const int tid = threadIdx.x;
  const int lane = tid & 63, w = tid >> 6;
  const int wm = (w >> 1) * 32, wn = (w & 1) * 64;
  const int lrow = lane & 15, kg = lane >> 4;
  const float g = gates[0];
  const f32x4 fz = {0.f, 0.f, 0.f, 0.f};
  f32x4 acc[2][4];
#pragma unroll
  for (int i = 0; i < 2; ++i)
#pragma unroll
    for (int j = 0; j < 4; ++j) acc[i][j] = fz;

  for (int k0 = 0; k0 < 1024; k0 += 64) {
    __syncthreads();
#pragma unroll
    for (int it = 0; it < 2; ++it) {
      int j = it * 512 + tid;
      int r = j >> 3, cl = j & 7;
      g2l16(smA + j * 8, aop + (size_t)(mbase + r) * 1024 + k0 + (cl ^ (r & 7)) * 8);
    }
#pragma unroll
    for (int it = 0; it < 2; ++it) {
      int j = it * 512 + tid;
      int r = j >> 3, cl = j & 7;
      g2l16(smB + j * 8, Wob + (size_t)(nbase + r) * 1024 + k0 + (cl ^ (r & 7)) * 8);
    }
    __syncthreads();
#pragma unroll
    for (int ks = 0; ks < 2; ++ks) {
      bf16x8 af[2], bfr[4];
#pragma unroll
      for (int mt = 0; mt < 2; ++mt) {
        int r = wm + mt * 16 + lrow;
        af[mt] = *(const bf16x8*)(smA + r * 64 + ((ks * 4 + kg) ^ (r & 7)) * 8);
      }
#pragma unroll
      for (int nt = 0; nt < 4; ++nt) {
        int r = wn + nt * 16 + lrow;
        bfr[nt] = *(const bf16x8*)(smB + r * 64 + ((ks * 4 + kg) ^ (r & 7)) * 8);
      }
#pragma unroll
      for (int nt = 0; nt < 4; ++nt)
#pragma unroll
        for (int mt = 0; mt < 2; ++mt)
          acc[mt][nt] = MFMA(af[mt], bfr[nt], acc[mt][nt]);
    }
  }
#pragma unroll
  for (int mt = 0; mt < 2; ++mt)
#pragma unroll
    for (int rg = 0; rg < 4; ++rg) {
      int m = mbase + wm + mt * 16 + kg * 4 + rg;
#pragma unroll
      for (int nt = 0; nt < 4; ++nt) {
        int n = nbase + wn + nt * 16 + lrow;
        out[(size_t)m * 1024 + n] = (acc[mt][nt][rg] + bo[n]) * g;
      }
    }
}

extern "C" void kernel_launch(void* const* d_in, const int* in_sizes, int n_in,
                              void* d_out, int out_size, void* d_ws, size_t ws_size,
                              hipStream_t stream) {
  const float* query = (const float*)d_in[0];
  const float* key   = (const float*)d_in[1];
  const float* value = (const float*)d_in[2];
  const float* mask  = (const float*)d_in[3];
  const float* pe    = (const float*)d_in[4];
  const float* Wq = (const float*)d_in[5];
  const float* bq = (const float*)d_in[6];
  const float* Wk = (const float*)d_in[7];
  const float* bk = (const float*)d_in[8];
  const float* Wv = (const float*)d_in[9];
  const float* bv = (const float*)d_in[10];
  const float* Wp = (const float*)d_in[11];
  const float* bp = (const float*)d_in[12];
  const float* Wo = (const float*)d_in[13];
  const float* bo = (const float*)d_in[14];
  const float* gates = (const float*)d_in[15];
  float* out = (float*)d_out;

  char* base = (char*)d_ws;
  size_t off = 0;
  bf16* wq_b = (bf16*)(base + off); off += 2097152;
  bf16* wk_b = (bf16*)(base + off); off += 2097152;
  bf16* wv_b = (bf16*)(base + off); off += 2097152;
  bf16* wo_b = (bf16*)(base + off); off += 2097152;
  bf16* wp_b = (bf16*)(base + off); off += 2097152;
  bf16* pe_b = (bf16*)(base + off); off += 819200;
  bf16* posq = (bf16*)(base + off); off += 819200;
  bf16* posk = (bf16*)(base + off); off += 819200;
  bf16* posv = (bf16*)(base + off); off += 819200;
  bf16* qb = (bf16*)(base + off); off += 26214400;
  bf16* kb = (bf16*)(base + off); off += 26214400;
  bf16* vt = (bf16*)(base + off); off += 26214400;
  bf16* ao = (bf16*)(base + off); off += 26214400;
  (void)ws_size; (void)in_sizes; (void)n_in; (void)out_size;

  cvt_all<<<5520, 256, 0, stream>>>(Wq, Wk, Wv, Wo, Wp, pe,
                                    wq_b, wk_b, wv_b, wo_b, wp_b, pe_b);
  gemm_pos<<<dim3(8, 4), 256, 0, stream>>>(pe_b, wp_b, bp, bq, bk, bv,
                                           posq, posk, posv);
  gemm_qkv<<<dim3(832, 3), 512, 0, stream>>>(query, key, value,
                                             wq_b, wk_b, wv_b,
                                             posq, posk, posv, qb, kb, vt);
  attn_kernel<<<2048, 512, 0, stream>>>(qb, kb, vt, mask, ao);
  gemm_out<<<832, 512, 0, stream>>>(ao, wo_b, bo, gates, out);
}